// Round 4
// baseline (298.301 us; speedup 1.0000x reference)
//
#include <hip/hip_runtime.h>
#include <cstdint>

// Problem constants (B=8, C=80, H=W=128, K=100, kernel=3, num_dets=1000)
#define NB    8
#define NC    80
#define HH    128
#define WW    128
#define HW    16384
#define CHW   1310720
#define KTOP  100
#define NDET  1000
#define NPAIR 10000
#define ACAP  2048
#define SCAP_MAX 262144   // per-(tensor,batch) survivor cap; expected ~145K

// ---- workspace layout (bytes) ----
#define OFF_SCNT   0                      // int[24*32]  (padded: one counter per 128B)
#define OFF_OVF    3072                   // int[24]
#define OFF_CS     3200                   // float[2400]
#define OFF_CX     12800
#define OFF_CY     22400
#define OFF_CE     32000
#define OFF_CCLS   41600                  // int[2400]
#define OFF_SURV   51200                  // uint64[24][scap]
#define ZERO_BYTES 3200

__device__ __forceinline__ float sigmoidf(float x) {
    if (x >= 0.f) return 1.f / (1.f + expf(-x));
    float e = expf(x);
    return e / (1.f + e);
}

// ---- kernel 1: NMS + wave-ballot survivor compaction (no LDS) ----
// Thread owns a 4x4 tile; loads 6 row-segments (y-1..y+4) up front (ILP=6).
// 32 lanes span one 128-wide row; lanes 0-31 rows ybase.., lanes 32-63 rows ybase+4..
__global__ void __launch_bounds__(256) k_nms(
        const float* __restrict__ tl, const float* __restrict__ br,
        const float* __restrict__ ct,
        uint64_t* __restrict__ surv, int* __restrict__ scnt,
        int* __restrict__ ovf, int scap) {
    int bc = blockIdx.y; int t = bc >> 3; int b = bc & 7;
    const float* heat = (t == 0) ? tl : (t == 1) ? br : ct;
    int chan = blockIdx.x >> 2;
    const float* cb = heat + (size_t)b * CHW + (size_t)chan * HW;
    int tid = threadIdx.x;
    int lane = tid & 63;
    int ybase = ((blockIdx.x & 3) << 5) + ((tid >> 6) << 3) + ((lane >> 5) << 2);
    int x0 = (lane & 31) << 2;
    const float NEG = -__builtin_inff();

    float4 L[6];
    #pragma unroll
    for (int r = 0; r < 6; ++r) {
        int yy = ybase - 1 + r;
        if (yy >= 0 && yy < HH) L[r] = *(const float4*)(cb + yy * WW + x0);
        else                    L[r] = make_float4(NEG, NEG, NEG, NEG);
    }

    uint32_t mask = 0;
    #pragma unroll
    for (int j = 0; j < 4; ++j) {
        float c0 = fmaxf(fmaxf(L[j].x, L[j+1].x), L[j+2].x);
        float c1 = fmaxf(fmaxf(L[j].y, L[j+1].y), L[j+2].y);
        float c2 = fmaxf(fmaxf(L[j].z, L[j+1].z), L[j+2].z);
        float c3 = fmaxf(fmaxf(L[j].w, L[j+1].w), L[j+2].w);
        float cl = __shfl_up(c3, 1);    // lanes 0,32 masked below (x0==0)
        float cr = __shfl_down(c0, 1);  // lanes 31,63 masked below (x0==124)
        if (x0 == 0)      cl = NEG;
        if (x0 == WW - 4) cr = NEG;
        if (fmaxf(fmaxf(cl, c0), c1) == L[j+1].x) mask |= 1u << (j*4+0);
        if (fmaxf(fmaxf(c0, c1), c2) == L[j+1].y) mask |= 1u << (j*4+1);
        if (fmaxf(fmaxf(c1, c2), c3) == L[j+1].z) mask |= 1u << (j*4+2);
        if (fmaxf(fmaxf(c2, c3), cr) == L[j+1].w) mask |= 1u << (j*4+3);
    }

    if (__ballot(mask != 0)) {
        uint32_t wavecnt = 0;
        #pragma unroll
        for (int k = 0; k < 16; ++k)
            wavecnt += (uint32_t)__popcll(__ballot((mask >> k) & 1));
        int gbase = 0;
        if (lane == 0) {
            gbase = atomicAdd(&scnt[bc * 32], (int)wavecnt);
            if (gbase + (int)wavecnt > scap) ovf[bc] = 1;
        }
        gbase = __shfl(gbase, 0);
        uint64_t ltm = (1ull << lane) - 1;
        uint32_t run = 0;
        uint64_t* sv = surv + (size_t)bc * scap;
        int ibase0 = chan * HW + ybase * WW + x0;
        #pragma unroll
        for (int j = 0; j < 4; ++j) {
            #pragma unroll
            for (int p = 0; p < 4; ++p) {
                bool bit = (mask >> (j * 4 + p)) & 1;
                uint64_t bl = __ballot(bit);
                if (bit) {
                    float v = (p == 0) ? L[j+1].x : (p == 1) ? L[j+1].y
                            : (p == 2) ? L[j+1].z : L[j+1].w;
                    uint32_t bt = __float_as_uint(sigmoidf(v));
                    int idx = ibase0 + j * WW + p;
                    int off = gbase + (int)run + (int)__popcll(bl & ltm);
                    if (off < scap)
                        sv[off] = ((uint64_t)bt << 32) | (uint32_t)(~(uint32_t)idx);
                }
                run += (uint32_t)__popcll(bl);
            }
        }
    }
}

// on-the-fly key for the (never-expected) survivor-overflow fallback
__device__ uint64_t key_at(const float* __restrict__ hb, int i) {
    float v = hb[i];
    int rem = i & (HW - 1);
    int y = rem >> 7, x = rem & (WW - 1);
    bool mx = true;
    if (y > 0) {
        if (x > 0      && hb[i - WW - 1] > v) mx = false;
        if (              hb[i - WW    ] > v) mx = false;
        if (x < WW - 1 && hb[i - WW + 1] > v) mx = false;
    }
    if (x > 0      && hb[i - 1] > v) mx = false;
    if (x < WW - 1 && hb[i + 1] > v) mx = false;
    if (y < HH - 1) {
        if (x > 0      && hb[i + WW - 1] > v) mx = false;
        if (              hb[i + WW    ] > v) mx = false;
        if (x < WW - 1 && hb[i + WW + 1] > v) mx = false;
    }
    if (!mx) return 0;
    return ((uint64_t)__float_as_uint(sigmoidf(v)) << 32) | (uint32_t)(~(uint32_t)i);
}

// descending bitonic sort of N u64 keys in LDS
template <int N>
__device__ void bitonic_desc(uint64_t* k) {
    for (int kk = 2; kk <= N; kk <<= 1) {
        for (int j = kk >> 1; j > 0; j >>= 1) {
            __syncthreads();
            for (int i = threadIdx.x; i < N; i += blockDim.x) {
                int l = i ^ j;
                if (l > i) {
                    uint64_t a = k[i], b = k[l];
                    bool up = ((i & kk) == 0);
                    if (up ? (a < b) : (a > b)) { k[i] = b; k[l] = a; }
                }
            }
        }
    }
    __syncthreads();
}

// ---- kernel 2: exact top-100 per (tensor,batch) via 64-bit radix select ----
// levels: 12+13+13+13+13 bits; keys unique -> pivot = exact rank-100 key.
__global__ void __launch_bounds__(1024) k_select100(
        const uint64_t* __restrict__ surv, const int* __restrict__ scnt,
        const int* __restrict__ ovf, int scap,
        const float* __restrict__ tl, const float* __restrict__ br,
        const float* __restrict__ ct,
        const float* __restrict__ tl_tag, const float* __restrict__ br_tag,
        const float* __restrict__ tl_regr, const float* __restrict__ br_regr,
        const float* __restrict__ ct_regr,
        float* __restrict__ cs, float* __restrict__ cx, float* __restrict__ cy,
        float* __restrict__ ce, int* __restrict__ ccls) {
    __shared__ unsigned int hist[8192];
    __shared__ unsigned int csum[1024];
    __shared__ uint64_t topk[128];
    __shared__ uint64_t prefix_sh;
    __shared__ int need_sh, done_sh, tcnt_sh;

    int bc = blockIdx.x; int t = bc >> 3; int b = bc & 7;
    const float* heat = (t == 0) ? tl : (t == 1) ? br : ct;
    const float* hb = heat + (size_t)b * CHW;
    int tid = threadIdx.x;
    int n = scnt[bc * 32];
    bool fb = (ovf[bc] != 0) || (n > scap);
    int nn = fb ? CHW : n;
    const uint64_t* sv = surv + (size_t)bc * scap;

    if (tid == 0) { prefix_sh = 0; need_sh = KTOP; done_sh = 0; tcnt_sh = 0; }

    for (int lvl = 0; lvl < 5; ++lvl) {
        int shift = (lvl == 0) ? 52 : 13 * (4 - lvl);
        for (int i = tid; i < 8192; i += 1024) hist[i] = 0;
        __syncthreads();
        if (!done_sh) {
            uint64_t pref = prefix_sh;
            if (lvl == 0) {
                // 4096 logical bins x 2 sub-histograms (halve hot-bin serialization)
                for (int i = tid; i < nn; i += 1024) {
                    uint64_t k = fb ? key_at(hb, i) : sv[i];
                    if (k) atomicAdd(&hist[(((uint32_t)(k >> 52)) << 1) | (tid & 1)], 1u);
                }
            } else {
                int topshift = shift + 13;
                for (int i = tid; i < nn; i += 1024) {
                    uint64_t k = fb ? key_at(hb, i) : sv[i];
                    if (k && (k >> topshift) == pref)
                        atomicAdd(&hist[(uint32_t)(k >> shift) & 8191u], 1u);
                }
            }
        }
        __syncthreads();
        unsigned int s = 0;
        if (lvl == 0) {
            #pragma unroll
            for (int i = 0; i < 4; ++i) {
                int bin = tid * 4 + i;
                s += hist[bin * 2] + hist[bin * 2 + 1];
            }
        } else {
            #pragma unroll
            for (int i = 0; i < 8; ++i) s += hist[tid * 8 + i];
        }
        csum[tid] = s;
        __syncthreads();
        for (int step = 1; step < 1024; step <<= 1) {
            unsigned int add = (tid + step < 1024) ? csum[tid + step] : 0;
            __syncthreads();
            csum[tid] += add;
            __syncthreads();
        }
        if (!done_sh) {
            int need = need_sh;
            unsigned int above = (tid < 1023) ? csum[tid + 1] : 0;
            if (tid == 0 && (int)csum[0] < need) done_sh = 1;  // <100 keys total (degenerate)
            if ((int)above < need && (int)csum[tid] >= need) {
                unsigned int cum = above, cumabove = above;
                int nbv = (lvl == 0) ? 4 : 8;
                int sel = 0;
                for (int i = nbv - 1; i >= 0; --i) {
                    int bin = tid * nbv + i;
                    unsigned int c = (lvl == 0) ? (hist[bin*2] + hist[bin*2+1]) : hist[bin];
                    if ((int)(cum + c) >= need) { sel = bin; cumabove = cum; break; }
                    cum += c;
                }
                prefix_sh = (lvl == 0) ? (uint64_t)sel : ((prefix_sh << 13) | (uint64_t)sel);
                need_sh = need - (int)cumabove;
            }
        }
        __syncthreads();
    }

    uint64_t pivot = done_sh ? 1ull : prefix_sh;
    for (int i = tid; i < nn; i += 1024) {
        uint64_t k = fb ? key_at(hb, i) : sv[i];
        if (k >= pivot) {
            int pos = atomicAdd(&tcnt_sh, 1);
            if (pos < 128) topk[pos] = k;
        }
    }
    __syncthreads();
    int cnt = tcnt_sh; if (cnt > 128) cnt = 128;
    for (int i = tid; i < 128; i += 1024) if (i >= cnt) topk[i] = 0;
    bitonic_desc<128>(topk);

    if (tid < KTOP) {
        uint64_t key = topk[tid];
        float s2 = __uint_as_float((uint32_t)(key >> 32));
        uint32_t idx = ~(uint32_t)key;
        int cls = (int)(idx >> 14);
        int rem = (int)(idx & (HW - 1));
        int y = rem >> 7, x = rem & (WW - 1);
        const float* regr = (t == 0) ? tl_regr : (t == 1) ? br_regr : ct_regr;
        float o0 = regr[((size_t)b * 2 + 0) * HW + rem];
        float o1 = regr[((size_t)b * 2 + 1) * HW + rem];
        float emb = 0.f;
        if (t == 0) emb = tl_tag[(size_t)b * HW + rem];
        else if (t == 1) emb = br_tag[(size_t)b * HW + rem];
        int o = bc * KTOP + tid;
        cs[o] = s2;
        cx[o] = (float)x + o0;
        cy[o] = (float)y + o1;
        ce[o] = emb;
        ccls[o] = cls;
    }
}

// ---- kernel 3: fused pairwise scoring + final top-1000 + centers ----
__global__ void __launch_bounds__(1024) k_pairfinal(
        const float* __restrict__ cs, const float* __restrict__ cx,
        const float* __restrict__ cy, const float* __restrict__ ce,
        const int* __restrict__ ccls, float* __restrict__ out) {
    int b = blockIdx.x;
    __shared__ float ts[KTOP], tx[KTOP], ty[KTOP], te[KTOP];
    __shared__ int   tc[KTOP];
    __shared__ float bs_[KTOP], bx[KTOP], by[KTOP], be[KTOP];
    __shared__ int   bcl[KTOP];
    __shared__ uint64_t acc[ACAP];
    __shared__ int aidx[ACAP];
    __shared__ int acnt_s;
    int tid = threadIdx.x;
    if (tid == 0) acnt_s = 0;
    if (tid < KTOP) {
        int o = (0 * NB + b) * KTOP + tid;
        ts[tid] = cs[o]; tx[tid] = cx[o]; ty[tid] = cy[o]; te[tid] = ce[o]; tc[tid] = ccls[o];
    } else if (tid >= 512 && tid < 512 + KTOP) {
        int k = tid - 512;
        int o = (1 * NB + b) * KTOP + k;
        bs_[k] = cs[o]; bx[k] = cx[o]; by[k] = cy[o]; be[k] = ce[o]; bcl[k] = ccls[o];
    }
    __syncthreads();
    for (int p = tid; p < NPAIR; p += 1024) {
        int i = p / KTOP, j = p - i * KTOP;
        bool rej = (tc[i] != bcl[j])
                 | (fabsf(te[i] - be[j]) > 0.5f)
                 | (bx[j] < tx[i])
                 | (by[j] < ty[i]);
        if (!rej) {
            float sc = (ts[i] + bs_[j]) * 0.5f;
            int pos = atomicAdd(&acnt_s, 1);
            if (pos < ACAP)
                acc[pos] = ((uint64_t)__float_as_uint(sc) << 32) | (uint32_t)(~(uint32_t)p);
        }
    }
    __syncthreads();
    int m = acnt_s; if (m > ACAP) m = ACAP;
    if (m <= 256) {
        for (int i = tid; i < 256; i += 1024) if (i >= m) acc[i] = 0;
        bitonic_desc<256>(acc);
    } else {
        for (int i = tid; i < ACAP; i += 1024) if (i >= m) acc[i] = 0;
        bitonic_desc<ACAP>(acc);
    }
    for (int i = tid; i < m; i += 1024) aidx[i] = (int)(~(uint32_t)acc[i]);
    __syncthreads();
    for (int d = tid; d < NDET; d += 1024) {
        int p; float sc;
        if (d < m) {
            p = aidx[d];
            sc = __uint_as_float((uint32_t)(acc[d] >> 32));
        } else {
            // (d-m)-th flat pair-index NOT in accepted set, ascending (stable -1 ties)
            int r = d - m;
            int idx = r;
            for (;;) {
                int c = 0;
                for (int a = 0; a < m; ++a) c += (aidx[a] <= idx) ? 1 : 0;
                int ni = r + c;
                if (ni == idx) break;
                idx = ni;
            }
            p = idx; sc = -1.f;
        }
        int i = p / KTOP, j = p - i * KTOP;
        int ot = (0 * NB + b) * KTOP + i;
        int ob = (1 * NB + b) * KTOP + j;
        float* dr = out + ((size_t)b * NDET + d) * 8;
        dr[0] = cx[ot]; dr[1] = cy[ot]; dr[2] = cx[ob]; dr[3] = cy[ob];
        dr[4] = sc; dr[5] = cs[ot]; dr[6] = cs[ob]; dr[7] = (float)ccls[ot];
    }
    if (tid < KTOP) {
        int oc = (2 * NB + b) * KTOP + tid;
        float* cr = out + (size_t)NB * NDET * 8 + ((size_t)b * KTOP + tid) * 4;
        cr[0] = cx[oc]; cr[1] = cy[oc]; cr[2] = (float)ccls[oc]; cr[3] = cs[oc];
    }
}

extern "C" void kernel_launch(void* const* d_in, const int* in_sizes, int n_in,
                              void* d_out, int out_size, void* d_ws, size_t ws_size,
                              hipStream_t stream) {
    const float* tl_heat = (const float*)d_in[0];
    const float* br_heat = (const float*)d_in[1];
    const float* ct_heat = (const float*)d_in[2];
    const float* tl_tag  = (const float*)d_in[3];
    const float* br_tag  = (const float*)d_in[4];
    const float* tl_regr = (const float*)d_in[5];
    const float* br_regr = (const float*)d_in[6];
    const float* ct_regr = (const float*)d_in[7];

    if (ws_size < (size_t)(OFF_SURV + 24 * 8 * 1024)) return;
    size_t rem = (ws_size - OFF_SURV) / (24 * 8);
    int scap = (int)((rem > SCAP_MAX) ? SCAP_MAX : rem);

    char* ws = (char*)d_ws;
    int*      scnt = (int*)(ws + OFF_SCNT);
    int*      ovf  = (int*)(ws + OFF_OVF);
    float*    cs   = (float*)(ws + OFF_CS);
    float*    cx   = (float*)(ws + OFF_CX);
    float*    cy   = (float*)(ws + OFF_CY);
    float*    ce   = (float*)(ws + OFF_CE);
    int*      ccls = (int*)(ws + OFF_CCLS);
    uint64_t* surv = (uint64_t*)(ws + OFF_SURV);

    hipMemsetAsync(ws, 0, ZERO_BYTES, stream);

    k_nms<<<dim3(320, 24), 256, 0, stream>>>(tl_heat, br_heat, ct_heat,
                                             surv, scnt, ovf, scap);
    k_select100<<<24, 1024, 0, stream>>>(surv, scnt, ovf, scap,
                                         tl_heat, br_heat, ct_heat,
                                         tl_tag, br_tag,
                                         tl_regr, br_regr, ct_regr,
                                         cs, cx, cy, ce, ccls);
    k_pairfinal<<<NB, 1024, 0, stream>>>(cs, cx, cy, ce, ccls, (float*)d_out);
}

// Round 5
// 177.209 us; speedup vs baseline: 1.6833x; 1.6833x over previous
//
#include <hip/hip_runtime.h>
#include <cstdint>

// Problem constants (B=8, C=80, H=W=128, K=100, kernel=3, num_dets=1000)
#define NB    8
#define NC    80
#define HH    128
#define WW    128
#define HW    16384
#define CHW   1310720
#define KTOP  100
#define NDET  1000
#define NPAIR 10000
#define CAP   4096
#define ACAP  2048
#define NBINS 4096
#define SCAP_MAX 262144   // per-(tensor,batch) survivor cap; expected ~145K

// ---- workspace layout (bytes) ----
#define OFF_SCNT   0                         // int[24] padded to 128B each
#define OFF_CCNT   3072                      // int[24] padded to 128B each
#define OFF_OVF    6144                      // int[24]
#define OFF_THR    6272                      // int[24]
#define OFF_HIST   6400                      // u32[24][4096]
#define OFF_CAND   399616                    // u64[24][4096]
#define OFF_CS     1186048                   // float[2400]
#define OFF_CX     1195648
#define OFF_CY     1205248
#define OFF_CE     1214848
#define OFF_CCLS   1224448                   // int[2400]
#define OFF_SURV   1234048                   // u64[24][scap]
#define ZERO_BYTES 399616                    // scnt..hist inclusive

__device__ __forceinline__ float sigmoidf(float x) {
    if (x >= 0.f) return 1.f / (1.f + expf(-x));
    float e = expf(x);
    return e / (1.f + e);
}

// ---- kernel 1: NMS + wave-ballot survivor compaction (no LDS) ----
// Thread owns a 4x4 tile; loads 6 row-segments (y-1..y+4) up front (ILP=6).
__global__ void __launch_bounds__(256) k_nms(
        const float* __restrict__ tl, const float* __restrict__ br,
        const float* __restrict__ ct,
        uint64_t* __restrict__ surv, int* __restrict__ scnt,
        int* __restrict__ ovf, int scap) {
    int bc = blockIdx.y; int t = bc >> 3; int b = bc & 7;
    const float* heat = (t == 0) ? tl : (t == 1) ? br : ct;
    int chan = blockIdx.x >> 2;
    const float* cb = heat + (size_t)b * CHW + (size_t)chan * HW;
    int tid = threadIdx.x;
    int lane = tid & 63;
    int ybase = ((blockIdx.x & 3) << 5) + ((tid >> 6) << 3) + ((lane >> 5) << 2);
    int x0 = (lane & 31) << 2;
    const float NEG = -__builtin_inff();

    float4 L[6];
    #pragma unroll
    for (int r = 0; r < 6; ++r) {
        int yy = ybase - 1 + r;
        if (yy >= 0 && yy < HH) L[r] = *(const float4*)(cb + yy * WW + x0);
        else                    L[r] = make_float4(NEG, NEG, NEG, NEG);
    }

    uint32_t mask = 0;
    #pragma unroll
    for (int j = 0; j < 4; ++j) {
        float c0 = fmaxf(fmaxf(L[j].x, L[j+1].x), L[j+2].x);
        float c1 = fmaxf(fmaxf(L[j].y, L[j+1].y), L[j+2].y);
        float c2 = fmaxf(fmaxf(L[j].z, L[j+1].z), L[j+2].z);
        float c3 = fmaxf(fmaxf(L[j].w, L[j+1].w), L[j+2].w);
        float cl = __shfl_up(c3, 1);
        float cr = __shfl_down(c0, 1);
        if (x0 == 0)      cl = NEG;
        if (x0 == WW - 4) cr = NEG;
        if (fmaxf(fmaxf(cl, c0), c1) == L[j+1].x) mask |= 1u << (j*4+0);
        if (fmaxf(fmaxf(c0, c1), c2) == L[j+1].y) mask |= 1u << (j*4+1);
        if (fmaxf(fmaxf(c1, c2), c3) == L[j+1].z) mask |= 1u << (j*4+2);
        if (fmaxf(fmaxf(c2, c3), cr) == L[j+1].w) mask |= 1u << (j*4+3);
    }

    if (__ballot(mask != 0)) {
        uint32_t wavecnt = 0;
        #pragma unroll
        for (int k = 0; k < 16; ++k)
            wavecnt += (uint32_t)__popcll(__ballot((mask >> k) & 1));
        int gbase = 0;
        if (lane == 0) {
            gbase = atomicAdd(&scnt[bc * 32], (int)wavecnt);
            if (gbase + (int)wavecnt > scap) ovf[bc] = 1;
        }
        gbase = __shfl(gbase, 0);
        uint64_t ltm = (1ull << lane) - 1;
        uint32_t run = 0;
        uint64_t* sv = surv + (size_t)bc * scap;
        int ibase0 = chan * HW + ybase * WW + x0;
        #pragma unroll
        for (int j = 0; j < 4; ++j) {
            #pragma unroll
            for (int p = 0; p < 4; ++p) {
                bool bit = (mask >> (j * 4 + p)) & 1;
                uint64_t bl = __ballot(bit);
                if (bit) {
                    float v = (p == 0) ? L[j+1].x : (p == 1) ? L[j+1].y
                            : (p == 2) ? L[j+1].z : L[j+1].w;
                    uint32_t bt = __float_as_uint(sigmoidf(v));
                    int idx = ibase0 + j * WW + p;
                    int off = gbase + (int)run + (int)__popcll(bl & ltm);
                    if (off < scap)
                        sv[off] = ((uint64_t)bt << 32) | (uint32_t)(~(uint32_t)idx);
                }
                run += (uint32_t)__popcll(bl);
            }
        }
    }
}

// on-the-fly key for the (never-expected) survivor-overflow fallback
__device__ uint64_t key_at(const float* __restrict__ hb, int i) {
    float v = hb[i];
    int rem = i & (HW - 1);
    int y = rem >> 7, x = rem & (WW - 1);
    bool mx = true;
    if (y > 0) {
        if (x > 0      && hb[i - WW - 1] > v) mx = false;
        if (              hb[i - WW    ] > v) mx = false;
        if (x < WW - 1 && hb[i - WW + 1] > v) mx = false;
    }
    if (x > 0      && hb[i - 1] > v) mx = false;
    if (x < WW - 1 && hb[i + 1] > v) mx = false;
    if (y < HH - 1) {
        if (x > 0      && hb[i + WW - 1] > v) mx = false;
        if (              hb[i + WW    ] > v) mx = false;
        if (x < WW - 1 && hb[i + WW + 1] > v) mx = false;
    }
    if (!mx) return 0;
    return ((uint64_t)__float_as_uint(sigmoidf(v)) << 32) | (uint32_t)(~(uint32_t)i);
}

// ---- kernel 2: histogram of survivor keys (4096 bins over sigmoid bits) ----
__global__ void __launch_bounds__(256) k_hist(
        const uint64_t* __restrict__ surv, const int* __restrict__ scnt,
        const int* __restrict__ ovf, int scap,
        const float* __restrict__ tl, const float* __restrict__ br,
        const float* __restrict__ ct, uint32_t* __restrict__ hist) {
    __shared__ uint32_t lh[NBINS];
    for (int i = threadIdx.x; i < NBINS; i += 256) lh[i] = 0;
    __syncthreads();
    int bc = blockIdx.y;
    int n = scnt[bc * 32];
    bool fb = (ovf[bc] != 0) || (n > scap);
    if (!fb) {
        const uint64_t* sv = surv + (size_t)bc * scap;
        for (int i = blockIdx.x * 256 + threadIdx.x; i < n; i += 256 * 8) {
            uint64_t k = sv[i];
            atomicAdd(&lh[(uint32_t)(k >> 51)], 1u);   // sigmoid-bits >> 19
        }
    } else {
        int t = bc >> 3; int b = bc & 7;
        const float* heat = (t == 0) ? tl : (t == 1) ? br : ct;
        const float* hb = heat + (size_t)b * CHW;
        for (int i = blockIdx.x * 256 + threadIdx.x; i < CHW; i += 256 * 8) {
            uint64_t k = key_at(hb, i);
            if (k) atomicAdd(&lh[(uint32_t)(k >> 51)], 1u);
        }
    }
    __syncthreads();
    uint32_t* gh = hist + (size_t)bc * NBINS;
    for (int i = threadIdx.x; i < NBINS; i += 256) {
        uint32_t c = lh[i];
        if (c) atomicAdd(&gh[i], c);
    }
}

// ---- kernel 3: parallel threshold find ----
__global__ void __launch_bounds__(256) k_thresh(const uint32_t* __restrict__ hist,
                                                int* __restrict__ thr) {
    __shared__ uint32_t csum[256];
    int bc = blockIdx.x;
    const uint32_t* h = hist + (size_t)bc * NBINS;
    int tid = threadIdx.x;
    uint32_t bins[16];
    #pragma unroll
    for (int i = 0; i < 16; ++i) bins[i] = h[tid * 16 + i];
    if (tid == 0) bins[0] = 0;  // bin 0 excluded
    uint32_t s = 0;
    #pragma unroll
    for (int i = 0; i < 16; ++i) s += bins[i];
    csum[tid] = s;
    __syncthreads();
    for (int step = 1; step < 256; step <<= 1) {
        uint32_t add = (tid + step < 256) ? csum[tid + step] : 0;
        __syncthreads();
        csum[tid] += add;
        __syncthreads();
    }
    uint32_t inc = csum[tid];
    uint32_t above = (tid + 1 < 256) ? csum[tid + 1] : 0;
    if (tid == 0 && inc < KTOP) thr[bc] = 1;
    if (above < KTOP && inc >= KTOP) {
        uint32_t cum = above;
        int T = 1;
        #pragma unroll
        for (int i = 15; i >= 0; --i) {
            cum += bins[i];
            if (cum >= KTOP) { T = tid * 16 + i; break; }
        }
        thr[bc] = T;
    }
}

// ---- kernel 4: filter survivors by bin >= T (fallback rescan folded in) ----
__global__ void __launch_bounds__(256) k_collect(
        const uint64_t* __restrict__ surv, const int* __restrict__ scnt,
        const int* __restrict__ ovf, int scap, const int* __restrict__ thr,
        const float* __restrict__ tl, const float* __restrict__ br,
        const float* __restrict__ ct,
        uint64_t* __restrict__ cand, int* __restrict__ ccnt) {
    int bc = blockIdx.y;
    int n = scnt[bc * 32];
    bool fb = (ovf[bc] != 0) || (n > scap);
    int T = thr[bc];
    if (!fb) {
        const uint64_t* sv = surv + (size_t)bc * scap;
        for (int i = blockIdx.x * 256 + threadIdx.x; i < n; i += 256 * 8) {
            uint64_t k = sv[i];
            if ((int)(uint32_t)(k >> 51) >= T) {
                int pos = atomicAdd(&ccnt[bc * 32], 1);
                if (pos < CAP) cand[(size_t)bc * CAP + pos] = k;
            }
        }
    } else {
        int t = bc >> 3; int b = bc & 7;
        const float* heat = (t == 0) ? tl : (t == 1) ? br : ct;
        const float* hb = heat + (size_t)b * CHW;
        for (int i = blockIdx.x * 256 + threadIdx.x; i < CHW; i += 256 * 8) {
            uint64_t k = key_at(hb, i);
            if (k && (int)(uint32_t)(k >> 51) >= T) {
                int pos = atomicAdd(&ccnt[bc * 32], 1);
                if (pos < CAP) cand[(size_t)bc * CAP + pos] = k;
            }
        }
    }
}

// descending bitonic sort of N u64 keys in LDS
template <int N>
__device__ void bitonic_desc(uint64_t* k) {
    for (int kk = 2; kk <= N; kk <<= 1) {
        for (int j = kk >> 1; j > 0; j >>= 1) {
            __syncthreads();
            for (int i = threadIdx.x; i < N; i += blockDim.x) {
                int l = i ^ j;
                if (l > i) {
                    uint64_t a = k[i], b = k[l];
                    bool up = ((i & kk) == 0);
                    if (up ? (a < b) : (a > b)) { k[i] = b; k[l] = a; }
                }
            }
        }
    }
    __syncthreads();
}

// ---- kernel 5: per (tensor,batch) sort candidates, emit top-100 corner data ----
__global__ void __launch_bounds__(1024) k_select(
        const uint64_t* __restrict__ cand, const int* __restrict__ ccnt,
        const float* __restrict__ tl_tag, const float* __restrict__ br_tag,
        const float* __restrict__ tl_regr, const float* __restrict__ br_regr,
        const float* __restrict__ ct_regr,
        float* __restrict__ cs, float* __restrict__ cx, float* __restrict__ cy,
        float* __restrict__ ce, int* __restrict__ ccls) {
    __shared__ uint64_t keys[CAP];
    int bc = blockIdx.x; int t = bc >> 3; int b = bc & 7;
    int n = ccnt[bc * 32]; if (n > CAP) n = CAP;
    if (n <= 512) {
        for (int i = threadIdx.x; i < 512; i += 1024)
            keys[i] = (i < n) ? cand[(size_t)bc * CAP + i] : 0ull;
        bitonic_desc<512>(keys);
    } else {
        for (int i = threadIdx.x; i < CAP; i += 1024)
            keys[i] = (i < n) ? cand[(size_t)bc * CAP + i] : 0ull;
        bitonic_desc<CAP>(keys);
    }
    if (threadIdx.x < KTOP) {
        uint64_t key = keys[threadIdx.x];
        float s = __uint_as_float((uint32_t)(key >> 32));
        uint32_t idx = ~(uint32_t)key;
        int cls = (int)(idx >> 14);
        int rem = (int)(idx & (HW - 1));
        int y = rem >> 7, x = rem & (WW - 1);
        const float* regr = (t == 0) ? tl_regr : (t == 1) ? br_regr : ct_regr;
        float o0 = regr[((size_t)b * 2 + 0) * HW + rem];
        float o1 = regr[((size_t)b * 2 + 1) * HW + rem];
        float emb = 0.f;
        if (t == 0) emb = tl_tag[(size_t)b * HW + rem];
        else if (t == 1) emb = br_tag[(size_t)b * HW + rem];
        int o = bc * KTOP + threadIdx.x;
        cs[o] = s;
        cx[o] = (float)x + o0;
        cy[o] = (float)y + o1;
        ce[o] = emb;
        ccls[o] = cls;
    }
}

// ---- kernel 6: fused pairwise scoring + final top-1000 + centers ----
__global__ void __launch_bounds__(1024) k_pairfinal(
        const float* __restrict__ cs, const float* __restrict__ cx,
        const float* __restrict__ cy, const float* __restrict__ ce,
        const int* __restrict__ ccls, float* __restrict__ out) {
    int b = blockIdx.x;
    __shared__ float ts[KTOP], tx[KTOP], ty[KTOP], te[KTOP];
    __shared__ int   tc[KTOP];
    __shared__ float bs_[KTOP], bx[KTOP], by[KTOP], be[KTOP];
    __shared__ int   bcl[KTOP];
    __shared__ uint64_t acc[ACAP];
    __shared__ int aidx[ACAP];
    __shared__ int acnt_s;
    int tid = threadIdx.x;
    if (tid == 0) acnt_s = 0;
    if (tid < KTOP) {
        int o = (0 * NB + b) * KTOP + tid;
        ts[tid] = cs[o]; tx[tid] = cx[o]; ty[tid] = cy[o]; te[tid] = ce[o]; tc[tid] = ccls[o];
    } else if (tid >= 512 && tid < 512 + KTOP) {
        int k = tid - 512;
        int o = (1 * NB + b) * KTOP + k;
        bs_[k] = cs[o]; bx[k] = cx[o]; by[k] = cy[o]; be[k] = ce[o]; bcl[k] = ccls[o];
    }
    __syncthreads();
    for (int p = tid; p < NPAIR; p += 1024) {
        int i = p / KTOP, j = p - i * KTOP;
        bool rej = (tc[i] != bcl[j])
                 | (fabsf(te[i] - be[j]) > 0.5f)
                 | (bx[j] < tx[i])
                 | (by[j] < ty[i]);
        if (!rej) {
            float sc = (ts[i] + bs_[j]) * 0.5f;
            int pos = atomicAdd(&acnt_s, 1);
            if (pos < ACAP)
                acc[pos] = ((uint64_t)__float_as_uint(sc) << 32) | (uint32_t)(~(uint32_t)p);
        }
    }
    __syncthreads();
    int m = acnt_s; if (m > ACAP) m = ACAP;
    if (m <= 256) {
        for (int i = tid; i < 256; i += 1024) if (i >= m) acc[i] = 0;
        bitonic_desc<256>(acc);
    } else {
        for (int i = tid; i < ACAP; i += 1024) if (i >= m) acc[i] = 0;
        bitonic_desc<ACAP>(acc);
    }
    for (int i = tid; i < m; i += 1024) aidx[i] = (int)(~(uint32_t)acc[i]);
    __syncthreads();
    for (int d = tid; d < NDET; d += 1024) {
        int p; float sc;
        if (d < m) {
            p = aidx[d];
            sc = __uint_as_float((uint32_t)(acc[d] >> 32));
        } else {
            // (d-m)-th flat pair-index NOT in accepted set, ascending (stable -1 ties)
            int r = d - m;
            int idx = r;
            for (;;) {
                int c = 0;
                for (int a = 0; a < m; ++a) c += (aidx[a] <= idx) ? 1 : 0;
                int ni = r + c;
                if (ni == idx) break;
                idx = ni;
            }
            p = idx; sc = -1.f;
        }
        int i = p / KTOP, j = p - i * KTOP;
        int ot = (0 * NB + b) * KTOP + i;
        int ob = (1 * NB + b) * KTOP + j;
        float* dr = out + ((size_t)b * NDET + d) * 8;
        dr[0] = cx[ot]; dr[1] = cy[ot]; dr[2] = cx[ob]; dr[3] = cy[ob];
        dr[4] = sc; dr[5] = cs[ot]; dr[6] = cs[ob]; dr[7] = (float)ccls[ot];
    }
    if (tid < KTOP) {
        int oc = (2 * NB + b) * KTOP + tid;
        float* cr = out + (size_t)NB * NDET * 8 + ((size_t)b * KTOP + tid) * 4;
        cr[0] = cx[oc]; cr[1] = cy[oc]; cr[2] = (float)ccls[oc]; cr[3] = cs[oc];
    }
}

extern "C" void kernel_launch(void* const* d_in, const int* in_sizes, int n_in,
                              void* d_out, int out_size, void* d_ws, size_t ws_size,
                              hipStream_t stream) {
    const float* tl_heat = (const float*)d_in[0];
    const float* br_heat = (const float*)d_in[1];
    const float* ct_heat = (const float*)d_in[2];
    const float* tl_tag  = (const float*)d_in[3];
    const float* br_tag  = (const float*)d_in[4];
    const float* tl_regr = (const float*)d_in[5];
    const float* br_regr = (const float*)d_in[6];
    const float* ct_regr = (const float*)d_in[7];

    if (ws_size < (size_t)(OFF_SURV + 24 * 8 * 1024)) return;
    size_t rem = (ws_size - OFF_SURV) / (24 * 8);
    int scap = (int)((rem > SCAP_MAX) ? SCAP_MAX : rem);

    char* ws = (char*)d_ws;
    int*      scnt = (int*)(ws + OFF_SCNT);
    int*      ccnt = (int*)(ws + OFF_CCNT);
    int*      ovf  = (int*)(ws + OFF_OVF);
    int*      thr  = (int*)(ws + OFF_THR);
    uint32_t* hist = (uint32_t*)(ws + OFF_HIST);
    uint64_t* cand = (uint64_t*)(ws + OFF_CAND);
    float*    cs   = (float*)(ws + OFF_CS);
    float*    cx   = (float*)(ws + OFF_CX);
    float*    cy   = (float*)(ws + OFF_CY);
    float*    ce   = (float*)(ws + OFF_CE);
    int*      ccls = (int*)(ws + OFF_CCLS);
    uint64_t* surv = (uint64_t*)(ws + OFF_SURV);

    hipMemsetAsync(ws, 0, ZERO_BYTES, stream);

    k_nms<<<dim3(320, 24), 256, 0, stream>>>(tl_heat, br_heat, ct_heat,
                                             surv, scnt, ovf, scap);
    k_hist<<<dim3(8, 24), 256, 0, stream>>>(surv, scnt, ovf, scap,
                                            tl_heat, br_heat, ct_heat, hist);
    k_thresh<<<24, 256, 0, stream>>>(hist, thr);
    k_collect<<<dim3(8, 24), 256, 0, stream>>>(surv, scnt, ovf, scap, thr,
                                               tl_heat, br_heat, ct_heat,
                                               cand, ccnt);
    k_select<<<24, 1024, 0, stream>>>(cand, ccnt, tl_tag, br_tag,
                                      tl_regr, br_regr, ct_regr,
                                      cs, cx, cy, ce, ccls);
    k_pairfinal<<<NB, 1024, 0, stream>>>(cs, cx, cy, ce, ccls, (float*)d_out);
}

// Round 6
// 158.874 us; speedup vs baseline: 1.8776x; 1.1154x over previous
//
#include <hip/hip_runtime.h>
#include <cstdint>

// Problem constants (B=8, C=80, H=W=128, K=100, kernel=3, num_dets=1000)
#define NB    8
#define NC    80
#define HH    128
#define WW    128
#define HW    16384
#define CHW   1310720
#define KTOP  100
#define NDET  1000
#define NPAIR 10000
#define CAP   4096
#define ACAP  2048
#define NBINS 4096
#define SCAP_MAX 262144   // per-(tensor,batch) survivor cap; expected ~145K

// ---- workspace layout (bytes) ----
#define OFF_SCNT   0                         // int[24*32] (one counter per 128B)
#define OFF_OVF    3072                      // int[24] (padded)
#define OFF_HIST   3200                      // u32[24][4096]
#define ZERO_BYTES 396416                    // scnt+ovf+hist
#define OFF_CS     396416                    // float[2400]
#define OFF_CX     406016
#define OFF_CY     415616
#define OFF_CE     425216
#define OFF_CCLS   434816                    // int[2400]
#define OFF_SURV   444416                    // u64[24][scap]

__device__ __forceinline__ float sigmoidf(float x) {
    if (x >= 0.f) return 1.f / (1.f + expf(-x));
    float e = expf(x);
    return e / (1.f + e);
}

// ---- kernel 1: NMS + survivor compaction, ILP-structured ----
// Thread owns a 4x8 tile: 10 unconditional row loads (clamped addr) issued
// back-to-back, then compute. 32 lanes span one 128-wide row.
__global__ void __launch_bounds__(256) k_nms(
        const float* __restrict__ tl, const float* __restrict__ br,
        const float* __restrict__ ct,
        uint64_t* __restrict__ surv, int* __restrict__ scnt,
        int* __restrict__ ovf, int scap) {
    int bc = blockIdx.y; int t = bc >> 3; int b = bc & 7;
    const float* heat = (t == 0) ? tl : (t == 1) ? br : ct;
    int chan = blockIdx.x >> 1;
    int half = blockIdx.x & 1;
    const float* cb = heat + (size_t)b * CHW + (size_t)chan * HW;
    int tid = threadIdx.x;
    int lane = tid & 63;
    int band = ((tid >> 6) << 1) + (lane >> 5);      // 0..7 within block
    int ybase = half * 64 + band * 8;                // 0..120
    int x0 = (lane & 31) << 2;
    const float NEG = -__builtin_inff();

    // 10 unconditional loads (clamped row address), all issued before compute
    float4 L[10];
    #pragma unroll
    for (int r = 0; r < 10; ++r) {
        int yy = ybase - 1 + r;
        int yc = min(max(yy, 0), HH - 1);
        L[r] = *(const float4*)(cb + yc * WW + x0);
    }
    __builtin_amdgcn_sched_barrier(0);
    if (ybase == 0)       L[0] = make_float4(NEG, NEG, NEG, NEG);
    if (ybase == HH - 8)  L[9] = make_float4(NEG, NEG, NEG, NEG);

    uint32_t mask = 0;
    #pragma unroll
    for (int j = 0; j < 8; ++j) {
        float c0 = fmaxf(fmaxf(L[j].x, L[j+1].x), L[j+2].x);
        float c1 = fmaxf(fmaxf(L[j].y, L[j+1].y), L[j+2].y);
        float c2 = fmaxf(fmaxf(L[j].z, L[j+1].z), L[j+2].z);
        float c3 = fmaxf(fmaxf(L[j].w, L[j+1].w), L[j+2].w);
        float cl = __shfl_up(c3, 1);    // cross-band pulls masked by x0 test
        float cr = __shfl_down(c0, 1);
        if (x0 == 0)      cl = NEG;
        if (x0 == WW - 4) cr = NEG;
        if (fmaxf(fmaxf(cl, c0), c1) == L[j+1].x) mask |= 1u << (j*4+0);
        if (fmaxf(fmaxf(c0, c1), c2) == L[j+1].y) mask |= 1u << (j*4+1);
        if (fmaxf(fmaxf(c1, c2), c3) == L[j+1].z) mask |= 1u << (j*4+2);
        if (fmaxf(fmaxf(c2, c3), cr) == L[j+1].w) mask |= 1u << (j*4+3);
    }

    // wave prefix-scan of survivor counts -> one atomic per wave
    int cnt = __popc(mask);
    int incl = cnt;
    #pragma unroll
    for (int d = 1; d < 64; d <<= 1) {
        int u = __shfl_up(incl, d);
        if (lane >= d) incl += u;
    }
    int total = __shfl(incl, 63);
    if (total) {
        int gbase = 0;
        if (lane == 0) {
            gbase = atomicAdd(&scnt[bc * 32], total);
            if (gbase + total > scap) ovf[bc] = 1;
        }
        gbase = __shfl(gbase, 0);
        int base = gbase + incl - cnt;
        uint64_t* sv = surv + (size_t)bc * scap;
        int ib = chan * HW + ybase * WW + x0;
        // static-unrolled bit walk (keeps L[] indexing compile-time)
        #pragma unroll
        for (int j = 0; j < 8; ++j) {
            #pragma unroll
            for (int p = 0; p < 4; ++p) {
                if (mask & (1u << (j * 4 + p))) {
                    float v = (p == 0) ? L[j+1].x : (p == 1) ? L[j+1].y
                            : (p == 2) ? L[j+1].z : L[j+1].w;
                    uint32_t bt = __float_as_uint(sigmoidf(v));
                    int idx = ib + j * WW + p;
                    if (base < scap)
                        sv[base] = ((uint64_t)bt << 32) | (uint32_t)(~(uint32_t)idx);
                    ++base;
                }
            }
        }
    }
}

// on-the-fly key for the (never-expected) survivor-overflow fallback
__device__ uint64_t key_at(const float* __restrict__ hb, int i) {
    float v = hb[i];
    int rem = i & (HW - 1);
    int y = rem >> 7, x = rem & (WW - 1);
    bool mx = true;
    if (y > 0) {
        if (x > 0      && hb[i - WW - 1] > v) mx = false;
        if (              hb[i - WW    ] > v) mx = false;
        if (x < WW - 1 && hb[i - WW + 1] > v) mx = false;
    }
    if (x > 0      && hb[i - 1] > v) mx = false;
    if (x < WW - 1 && hb[i + 1] > v) mx = false;
    if (y < HH - 1) {
        if (x > 0      && hb[i + WW - 1] > v) mx = false;
        if (              hb[i + WW    ] > v) mx = false;
        if (x < WW - 1 && hb[i + WW + 1] > v) mx = false;
    }
    if (!mx) return 0;
    return ((uint64_t)__float_as_uint(sigmoidf(v)) << 32) | (uint32_t)(~(uint32_t)i);
}

// ---- kernel 2: histogram of survivor keys (4096 bins over sigmoid bits) ----
__global__ void __launch_bounds__(256) k_hist(
        const uint64_t* __restrict__ surv, const int* __restrict__ scnt,
        const int* __restrict__ ovf, int scap,
        const float* __restrict__ tl, const float* __restrict__ br,
        const float* __restrict__ ct, uint32_t* __restrict__ hist) {
    __shared__ uint32_t lh[NBINS];
    for (int i = threadIdx.x; i < NBINS; i += 256) lh[i] = 0;
    __syncthreads();
    int bc = blockIdx.y;
    int n = scnt[bc * 32];
    bool fb = (ovf[bc] != 0) || (n > scap);
    if (!fb) {
        const uint64_t* sv = surv + (size_t)bc * scap;
        for (int i = blockIdx.x * 256 + threadIdx.x; i < n; i += 256 * 16) {
            uint64_t k = sv[i];
            atomicAdd(&lh[(uint32_t)(k >> 51)], 1u);
        }
    } else {
        int t = bc >> 3; int b = bc & 7;
        const float* heat = (t == 0) ? tl : (t == 1) ? br : ct;
        const float* hb = heat + (size_t)b * CHW;
        for (int i = blockIdx.x * 256 + threadIdx.x; i < CHW; i += 256 * 16) {
            uint64_t k = key_at(hb, i);
            if (k) atomicAdd(&lh[(uint32_t)(k >> 51)], 1u);
        }
    }
    __syncthreads();
    uint32_t* gh = hist + (size_t)bc * NBINS;
    for (int i = threadIdx.x; i < NBINS; i += 256) {
        uint32_t c = lh[i];
        if (c) atomicAdd(&gh[i], c);
    }
}

// descending bitonic sort of N u64 keys in LDS
template <int N>
__device__ void bitonic_desc(uint64_t* k) {
    for (int kk = 2; kk <= N; kk <<= 1) {
        for (int j = kk >> 1; j > 0; j >>= 1) {
            __syncthreads();
            for (int i = threadIdx.x; i < N; i += blockDim.x) {
                int l = i ^ j;
                if (l > i) {
                    uint64_t a = k[i], b = k[l];
                    bool up = ((i & kk) == 0);
                    if (up ? (a < b) : (a > b)) { k[i] = b; k[l] = a; }
                }
            }
        }
    }
    __syncthreads();
}

// ---- kernel 3: fused threshold + filter + sort + emit top-100 ----
__global__ void __launch_bounds__(1024) k_collectsel(
        const uint32_t* __restrict__ hist,
        const uint64_t* __restrict__ surv, const int* __restrict__ scnt,
        const int* __restrict__ ovf, int scap,
        const float* __restrict__ tl, const float* __restrict__ br,
        const float* __restrict__ ct,
        const float* __restrict__ tl_tag, const float* __restrict__ br_tag,
        const float* __restrict__ tl_regr, const float* __restrict__ br_regr,
        const float* __restrict__ ct_regr,
        float* __restrict__ cs, float* __restrict__ cx, float* __restrict__ cy,
        float* __restrict__ ce, int* __restrict__ ccls) {
    __shared__ uint32_t csum[1024];
    __shared__ uint64_t keys[CAP];
    __shared__ int thr_s, cnt_s;
    int bc = blockIdx.x; int t = bc >> 3; int b = bc & 7;
    int tid = threadIdx.x;
    if (tid == 0) cnt_s = 0;

    // --- threshold: suffix-scan over 4096 bins, 4 bins/thread ---
    const uint32_t* h = hist + (size_t)bc * NBINS;
    uint32_t bins[4];
    #pragma unroll
    for (int i = 0; i < 4; ++i) bins[i] = h[tid * 4 + i];
    if (tid == 0) bins[0] = 0;  // bin 0 excluded
    uint32_t s = bins[0] + bins[1] + bins[2] + bins[3];
    csum[tid] = s;
    __syncthreads();
    for (int step = 1; step < 1024; step <<= 1) {
        uint32_t add = (tid + step < 1024) ? csum[tid + step] : 0;
        __syncthreads();
        csum[tid] += add;
        __syncthreads();
    }
    uint32_t above = (tid < 1023) ? csum[tid + 1] : 0;
    if (tid == 0 && (int)csum[0] < KTOP) thr_s = 1;
    if ((int)above < KTOP && (int)csum[tid] >= KTOP) {
        uint32_t cum = above;
        int T = 1;
        #pragma unroll
        for (int i = 3; i >= 0; --i) {
            cum += bins[i];
            if ((int)cum >= KTOP) { T = tid * 4 + i; break; }
        }
        thr_s = T;
    }
    __syncthreads();
    int T = thr_s;

    // --- filter survivors >= T into LDS ---
    int n = scnt[bc * 32];
    bool fb = (ovf[bc] != 0) || (n > scap);
    if (!fb) {
        const uint64_t* sv = surv + (size_t)bc * scap;
        for (int i = tid; i < n; i += 1024) {
            uint64_t k = sv[i];
            if ((int)(uint32_t)(k >> 51) >= T) {
                int pos = atomicAdd(&cnt_s, 1);
                if (pos < CAP) keys[pos] = k;
            }
        }
    } else {
        const float* heat = (t == 0) ? tl : (t == 1) ? br : ct;
        const float* hb = heat + (size_t)b * CHW;
        for (int i = tid; i < CHW; i += 1024) {
            uint64_t k = key_at(hb, i);
            if (k && (int)(uint32_t)(k >> 51) >= T) {
                int pos = atomicAdd(&cnt_s, 1);
                if (pos < CAP) keys[pos] = k;
            }
        }
    }
    __syncthreads();
    int cnt = cnt_s; if (cnt > CAP) cnt = CAP;
    if (cnt <= 512) {
        for (int i = tid; i < 512; i += 1024) if (i >= cnt) keys[i] = 0;
        bitonic_desc<512>(keys);
    } else {
        for (int i = tid; i < CAP; i += 1024) if (i >= cnt) keys[i] = 0;
        bitonic_desc<CAP>(keys);
    }

    // --- emit top-100 corner data ---
    if (tid < KTOP) {
        uint64_t key = keys[tid];
        float s2 = __uint_as_float((uint32_t)(key >> 32));
        uint32_t idx = ~(uint32_t)key;
        int cls = (int)(idx >> 14);
        int rem = (int)(idx & (HW - 1));
        int y = rem >> 7, x = rem & (WW - 1);
        const float* regr = (t == 0) ? tl_regr : (t == 1) ? br_regr : ct_regr;
        float o0 = regr[((size_t)b * 2 + 0) * HW + rem];
        float o1 = regr[((size_t)b * 2 + 1) * HW + rem];
        float emb = 0.f;
        if (t == 0) emb = tl_tag[(size_t)b * HW + rem];
        else if (t == 1) emb = br_tag[(size_t)b * HW + rem];
        int o = bc * KTOP + tid;
        cs[o] = s2;
        cx[o] = (float)x + o0;
        cy[o] = (float)y + o1;
        ce[o] = emb;
        ccls[o] = cls;
    }
}

// ---- kernel 4: fused pairwise scoring + final top-1000 + centers ----
__global__ void __launch_bounds__(1024) k_pairfinal(
        const float* __restrict__ cs, const float* __restrict__ cx,
        const float* __restrict__ cy, const float* __restrict__ ce,
        const int* __restrict__ ccls, float* __restrict__ out) {
    int b = blockIdx.x;
    __shared__ float ts[KTOP], tx[KTOP], ty[KTOP], te[KTOP];
    __shared__ int   tc[KTOP];
    __shared__ float bs_[KTOP], bx[KTOP], by[KTOP], be[KTOP];
    __shared__ int   bcl[KTOP];
    __shared__ uint64_t acc[ACAP];
    __shared__ int aidx[ACAP];
    __shared__ int acnt_s;
    int tid = threadIdx.x;
    if (tid == 0) acnt_s = 0;
    if (tid < KTOP) {
        int o = (0 * NB + b) * KTOP + tid;
        ts[tid] = cs[o]; tx[tid] = cx[o]; ty[tid] = cy[o]; te[tid] = ce[o]; tc[tid] = ccls[o];
    } else if (tid >= 512 && tid < 512 + KTOP) {
        int k = tid - 512;
        int o = (1 * NB + b) * KTOP + k;
        bs_[k] = cs[o]; bx[k] = cx[o]; by[k] = cy[o]; be[k] = ce[o]; bcl[k] = ccls[o];
    }
    __syncthreads();
    for (int p = tid; p < NPAIR; p += 1024) {
        int i = p / KTOP, j = p - i * KTOP;
        bool rej = (tc[i] != bcl[j])
                 | (fabsf(te[i] - be[j]) > 0.5f)
                 | (bx[j] < tx[i])
                 | (by[j] < ty[i]);
        if (!rej) {
            float sc = (ts[i] + bs_[j]) * 0.5f;
            int pos = atomicAdd(&acnt_s, 1);
            if (pos < ACAP)
                acc[pos] = ((uint64_t)__float_as_uint(sc) << 32) | (uint32_t)(~(uint32_t)p);
        }
    }
    __syncthreads();
    int m = acnt_s; if (m > ACAP) m = ACAP;
    if (m <= 256) {
        for (int i = tid; i < 256; i += 1024) if (i >= m) acc[i] = 0;
        bitonic_desc<256>(acc);
    } else {
        for (int i = tid; i < ACAP; i += 1024) if (i >= m) acc[i] = 0;
        bitonic_desc<ACAP>(acc);
    }
    for (int i = tid; i < m; i += 1024) aidx[i] = (int)(~(uint32_t)acc[i]);
    __syncthreads();
    for (int d = tid; d < NDET; d += 1024) {
        int p; float sc;
        if (d < m) {
            p = aidx[d];
            sc = __uint_as_float((uint32_t)(acc[d] >> 32));
        } else {
            // (d-m)-th flat pair-index NOT in accepted set, ascending (stable -1 ties)
            int r = d - m;
            int idx = r;
            for (;;) {
                int c = 0;
                for (int a = 0; a < m; ++a) c += (aidx[a] <= idx) ? 1 : 0;
                int ni = r + c;
                if (ni == idx) break;
                idx = ni;
            }
            p = idx; sc = -1.f;
        }
        int i = p / KTOP, j = p - i * KTOP;
        int ot = (0 * NB + b) * KTOP + i;
        int ob = (1 * NB + b) * KTOP + j;
        float* dr = out + ((size_t)b * NDET + d) * 8;
        dr[0] = cx[ot]; dr[1] = cy[ot]; dr[2] = cx[ob]; dr[3] = cy[ob];
        dr[4] = sc; dr[5] = cs[ot]; dr[6] = cs[ob]; dr[7] = (float)ccls[ot];
    }
    if (tid < KTOP) {
        int oc = (2 * NB + b) * KTOP + tid;
        float* cr = out + (size_t)NB * NDET * 8 + ((size_t)b * KTOP + tid) * 4;
        cr[0] = cx[oc]; cr[1] = cy[oc]; cr[2] = (float)ccls[oc]; cr[3] = cs[oc];
    }
}

extern "C" void kernel_launch(void* const* d_in, const int* in_sizes, int n_in,
                              void* d_out, int out_size, void* d_ws, size_t ws_size,
                              hipStream_t stream) {
    const float* tl_heat = (const float*)d_in[0];
    const float* br_heat = (const float*)d_in[1];
    const float* ct_heat = (const float*)d_in[2];
    const float* tl_tag  = (const float*)d_in[3];
    const float* br_tag  = (const float*)d_in[4];
    const float* tl_regr = (const float*)d_in[5];
    const float* br_regr = (const float*)d_in[6];
    const float* ct_regr = (const float*)d_in[7];

    if (ws_size < (size_t)(OFF_SURV + 24 * 8 * 1024)) return;
    size_t rem = (ws_size - OFF_SURV) / (24 * 8);
    int scap = (int)((rem > SCAP_MAX) ? SCAP_MAX : rem);

    char* ws = (char*)d_ws;
    int*      scnt = (int*)(ws + OFF_SCNT);
    int*      ovf  = (int*)(ws + OFF_OVF);
    uint32_t* hist = (uint32_t*)(ws + OFF_HIST);
    float*    cs   = (float*)(ws + OFF_CS);
    float*    cx   = (float*)(ws + OFF_CX);
    float*    cy   = (float*)(ws + OFF_CY);
    float*    ce   = (float*)(ws + OFF_CE);
    int*      ccls = (int*)(ws + OFF_CCLS);
    uint64_t* surv = (uint64_t*)(ws + OFF_SURV);

    hipMemsetAsync(ws, 0, ZERO_BYTES, stream);

    k_nms<<<dim3(160, 24), 256, 0, stream>>>(tl_heat, br_heat, ct_heat,
                                             surv, scnt, ovf, scap);
    k_hist<<<dim3(16, 24), 256, 0, stream>>>(surv, scnt, ovf, scap,
                                             tl_heat, br_heat, ct_heat, hist);
    k_collectsel<<<24, 1024, 0, stream>>>(hist, surv, scnt, ovf, scap,
                                          tl_heat, br_heat, ct_heat,
                                          tl_tag, br_tag,
                                          tl_regr, br_regr, ct_regr,
                                          cs, cx, cy, ce, ccls);
    k_pairfinal<<<NB, 1024, 0, stream>>>(cs, cx, cy, ce, ccls, (float*)d_out);
}

// Round 7
// 116.265 us; speedup vs baseline: 2.5657x; 1.3665x over previous
//
#include <hip/hip_runtime.h>
#include <cstdint>

// Problem constants (B=8, C=80, H=W=128, K=100, kernel=3, num_dets=1000)
#define NB    8
#define NC    80
#define HH    128
#define WW    128
#define HW    16384
#define CHW   1310720
#define KTOP  100
#define NDET  1000
#define NPAIR 10000
#define CAP   4096
#define ACAP  2048
#define NBINS 4096
#define BLK_SURV 1024     // LDS survivor staging cap per block (expect ~900)
#define SCAP_MAX 262144   // per-(tensor,batch) survivor cap; expected ~145K

// ---- workspace layout (bytes) ----
#define OFF_SCNT   0                         // int[24*32] (one counter per 128B)
#define OFF_OVF    3072                      // int[24] (padded)
#define OFF_HIST   3200                      // u32[24][4096]
#define ZERO_BYTES 396416                    // scnt+ovf+hist
#define OFF_CS     396416                    // float[2400]
#define OFF_CX     406016
#define OFF_CY     415616
#define OFF_CE     425216
#define OFF_CCLS   434816                    // int[2400]
#define OFF_SURV   444416                    // u64[24][scap]

// branchless, bit-identical to jax.nn.sigmoid's two-branch form:
// x>=0: 1/(1+exp(-x));  x<0: exp(x)/(1+exp(x));  exp(-|x|) covers both.
__device__ __forceinline__ float sigmoidf(float x) {
    float e = expf(-fabsf(x));
    return (x >= 0.f ? 1.f : e) / (1.f + e);
}

// ---- kernel 1: NMS + fused histogram + compacted survivor emission ----
// Phase A: 10 pinned row loads, stencil -> 32-bit mask (4 px wide x 8 rows).
// Phase B: block prefix-scan, stage (vbits,idx) to LDS (no sigmoid, no atomics).
// Phase C: dense sigmoid + LDS hist + coalesced global survivor store.
__global__ void __launch_bounds__(256) k_nms(
        const float* __restrict__ tl, const float* __restrict__ br,
        const float* __restrict__ ct,
        uint64_t* __restrict__ surv, int* __restrict__ scnt,
        int* __restrict__ ovf, uint32_t* __restrict__ hist, int scap) {
    __shared__ uint32_t lh[NBINS];          // 16 KB
    __shared__ uint2    lsurv[BLK_SURV];    // 8 KB
    __shared__ int      woff[4];
    __shared__ int      gbase_s, tot_s;

    int tid = threadIdx.x;
    for (int i = tid; i < NBINS; i += 256) lh[i] = 0;

    int bc = blockIdx.y; int t = bc >> 3; int b = bc & 7;
    const float* heat = (t == 0) ? tl : (t == 1) ? br : ct;
    int chan = blockIdx.x >> 1;
    int half = blockIdx.x & 1;
    const float* cb = heat + (size_t)b * CHW + (size_t)chan * HW;
    int lane = tid & 63;
    int wid = tid >> 6;
    int band = (wid << 1) + (lane >> 5);             // 0..7
    int ybase = half * 64 + band * 8;                // 0..120
    int x0 = (lane & 31) << 2;
    const float NEG = -__builtin_inff();

    // ---- phase A: 10 unconditional loads, pinned live ----
    float4 L[10];
    #pragma unroll
    for (int r = 0; r < 10; ++r) {
        int yy = ybase - 1 + r;
        int yc = min(max(yy, 0), HH - 1);
        L[r] = *(const float4*)(cb + yc * WW + x0);
    }
    #pragma unroll
    for (int r = 0; r < 10; ++r)
        asm volatile("" : "+v"(L[r].x), "+v"(L[r].y), "+v"(L[r].z), "+v"(L[r].w));
    if (ybase == 0)       L[0] = make_float4(NEG, NEG, NEG, NEG);
    if (ybase == HH - 8)  L[9] = make_float4(NEG, NEG, NEG, NEG);

    uint32_t mask = 0;
    #pragma unroll
    for (int j = 0; j < 8; ++j) {
        float c0 = fmaxf(fmaxf(L[j].x, L[j+1].x), L[j+2].x);
        float c1 = fmaxf(fmaxf(L[j].y, L[j+1].y), L[j+2].y);
        float c2 = fmaxf(fmaxf(L[j].z, L[j+1].z), L[j+2].z);
        float c3 = fmaxf(fmaxf(L[j].w, L[j+1].w), L[j+2].w);
        float cl = __shfl_up(c3, 1);     // cross-row pulls masked by x0 tests
        float cr = __shfl_down(c0, 1);
        if (x0 == 0)      cl = NEG;
        if (x0 == WW - 4) cr = NEG;
        if (fmaxf(fmaxf(cl, c0), c1) == L[j+1].x) mask |= 1u << (j*4+0);
        if (fmaxf(fmaxf(c0, c1), c2) == L[j+1].y) mask |= 1u << (j*4+1);
        if (fmaxf(fmaxf(c1, c2), c3) == L[j+1].z) mask |= 1u << (j*4+2);
        if (fmaxf(fmaxf(c2, c3), cr) == L[j+1].w) mask |= 1u << (j*4+3);
    }

    // ---- phase B: block-wide compaction into LDS ----
    int cnt = __popc(mask);
    int incl = cnt;
    #pragma unroll
    for (int d = 1; d < 64; d <<= 1) {
        int u = __shfl_up(incl, d);
        if (lane >= d) incl += u;
    }
    if (lane == 63) woff[wid] = incl;
    __syncthreads();
    if (tid == 0) {
        int s = 0;
        #pragma unroll
        for (int w = 0; w < 4; ++w) { int tw = woff[w]; woff[w] = s; s += tw; }
        tot_s = s;
        int gb = atomicAdd(&scnt[bc * 32], s);
        gbase_s = gb;
        if (s > BLK_SURV || gb + s > scap) ovf[bc] = 1;
    }
    __syncthreads();
    int base = woff[wid] + incl - cnt;
    if (mask) {
        int ib = chan * HW + ybase * WW + x0;
        #pragma unroll
        for (int j = 0; j < 8; ++j) {
            #pragma unroll
            for (int p = 0; p < 4; ++p) {
                if (mask & (1u << (j * 4 + p))) {
                    float v = (p == 0) ? L[j+1].x : (p == 1) ? L[j+1].y
                            : (p == 2) ? L[j+1].z : L[j+1].w;
                    if (base < BLK_SURV)
                        lsurv[base] = make_uint2(__float_as_uint(v),
                                                 (uint32_t)(ib + j * WW + p));
                    ++base;
                }
            }
        }
    }
    __syncthreads();

    // ---- phase C: dense sigmoid + hist + coalesced store ----
    int total = tot_s; if (total > BLK_SURV) total = BLK_SURV;
    int gb = gbase_s;
    uint64_t* sv = surv + (size_t)bc * scap;
    for (int i = tid; i < total; i += 256) {
        uint2 e = lsurv[i];
        uint32_t bt = __float_as_uint(sigmoidf(__uint_as_float(e.x)));
        atomicAdd(&lh[bt >> 19], 1u);
        if (gb + i < scap)
            sv[gb + i] = ((uint64_t)bt << 32) | (uint32_t)(~e.y);
    }
    __syncthreads();
    uint32_t* gh = hist + (size_t)bc * NBINS;
    for (int i = tid; i < NBINS; i += 256) {
        uint32_t c = lh[i];
        if (c) atomicAdd(&gh[i], c);
    }
}

// on-the-fly key for the (never-expected) survivor-overflow fallback
__device__ uint64_t key_at(const float* __restrict__ hb, int i) {
    float v = hb[i];
    int rem = i & (HW - 1);
    int y = rem >> 7, x = rem & (WW - 1);
    bool mx = true;
    if (y > 0) {
        if (x > 0      && hb[i - WW - 1] > v) mx = false;
        if (              hb[i - WW    ] > v) mx = false;
        if (x < WW - 1 && hb[i - WW + 1] > v) mx = false;
    }
    if (x > 0      && hb[i - 1] > v) mx = false;
    if (x < WW - 1 && hb[i + 1] > v) mx = false;
    if (y < HH - 1) {
        if (x > 0      && hb[i + WW - 1] > v) mx = false;
        if (              hb[i + WW    ] > v) mx = false;
        if (x < WW - 1 && hb[i + WW + 1] > v) mx = false;
    }
    if (!mx) return 0;
    return ((uint64_t)__float_as_uint(sigmoidf(v)) << 32) | (uint32_t)(~(uint32_t)i);
}

// descending bitonic sort of N u64 keys in LDS
template <int N>
__device__ void bitonic_desc(uint64_t* k) {
    for (int kk = 2; kk <= N; kk <<= 1) {
        for (int j = kk >> 1; j > 0; j >>= 1) {
            __syncthreads();
            for (int i = threadIdx.x; i < N; i += blockDim.x) {
                int l = i ^ j;
                if (l > i) {
                    uint64_t a = k[i], b = k[l];
                    bool up = ((i & kk) == 0);
                    if (up ? (a < b) : (a > b)) { k[i] = b; k[l] = a; }
                }
            }
        }
    }
    __syncthreads();
}

// ---- kernel 2: fused threshold + filter + sort + emit top-100 ----
__global__ void __launch_bounds__(1024) k_collectsel(
        const uint32_t* __restrict__ hist,
        const uint64_t* __restrict__ surv, const int* __restrict__ scnt,
        const int* __restrict__ ovf, int scap,
        const float* __restrict__ tl, const float* __restrict__ br,
        const float* __restrict__ ct,
        const float* __restrict__ tl_tag, const float* __restrict__ br_tag,
        const float* __restrict__ tl_regr, const float* __restrict__ br_regr,
        const float* __restrict__ ct_regr,
        float* __restrict__ cs, float* __restrict__ cx, float* __restrict__ cy,
        float* __restrict__ ce, int* __restrict__ ccls) {
    __shared__ uint32_t csum[1024];
    __shared__ uint64_t keys[CAP];
    __shared__ int thr_s, cnt_s;
    int bc = blockIdx.x; int t = bc >> 3; int b = bc & 7;
    int tid = threadIdx.x;
    if (tid == 0) cnt_s = 0;

    // threshold: suffix-scan over 4096 bins, 4 bins/thread
    const uint32_t* h = hist + (size_t)bc * NBINS;
    uint32_t bins[4];
    #pragma unroll
    for (int i = 0; i < 4; ++i) bins[i] = h[tid * 4 + i];
    if (tid == 0) bins[0] = 0;  // bin 0 excluded
    uint32_t s = bins[0] + bins[1] + bins[2] + bins[3];
    csum[tid] = s;
    __syncthreads();
    for (int step = 1; step < 1024; step <<= 1) {
        uint32_t add = (tid + step < 1024) ? csum[tid + step] : 0;
        __syncthreads();
        csum[tid] += add;
        __syncthreads();
    }
    uint32_t above = (tid < 1023) ? csum[tid + 1] : 0;
    if (tid == 0 && (int)csum[0] < KTOP) thr_s = 1;
    if ((int)above < KTOP && (int)csum[tid] >= KTOP) {
        uint32_t cum = above;
        int T = 1;
        #pragma unroll
        for (int i = 3; i >= 0; --i) {
            cum += bins[i];
            if ((int)cum >= KTOP) { T = tid * 4 + i; break; }
        }
        thr_s = T;
    }
    __syncthreads();
    int T = thr_s;

    // filter survivors >= T into LDS
    int n = scnt[bc * 32];
    bool fb = (ovf[bc] != 0) || (n > scap);
    if (!fb) {
        const uint64_t* sv = surv + (size_t)bc * scap;
        for (int i = tid; i < n; i += 1024) {
            uint64_t k = sv[i];
            if ((int)(uint32_t)(k >> 51) >= T) {
                int pos = atomicAdd(&cnt_s, 1);
                if (pos < CAP) keys[pos] = k;
            }
        }
    } else {
        const float* heat = (t == 0) ? tl : (t == 1) ? br : ct;
        const float* hb = heat + (size_t)b * CHW;
        for (int i = tid; i < CHW; i += 1024) {
            uint64_t k = key_at(hb, i);
            if (k && (int)(uint32_t)(k >> 51) >= T) {
                int pos = atomicAdd(&cnt_s, 1);
                if (pos < CAP) keys[pos] = k;
            }
        }
    }
    __syncthreads();
    int cnt = cnt_s; if (cnt > CAP) cnt = CAP;
    if (cnt <= 512) {
        for (int i = tid; i < 512; i += 1024) if (i >= cnt) keys[i] = 0;
        bitonic_desc<512>(keys);
    } else {
        for (int i = tid; i < CAP; i += 1024) if (i >= cnt) keys[i] = 0;
        bitonic_desc<CAP>(keys);
    }

    // emit top-100 corner data
    if (tid < KTOP) {
        uint64_t key = keys[tid];
        float s2 = __uint_as_float((uint32_t)(key >> 32));
        uint32_t idx = ~(uint32_t)key;
        int cls = (int)(idx >> 14);
        int rem = (int)(idx & (HW - 1));
        int y = rem >> 7, x = rem & (WW - 1);
        const float* regr = (t == 0) ? tl_regr : (t == 1) ? br_regr : ct_regr;
        float o0 = regr[((size_t)b * 2 + 0) * HW + rem];
        float o1 = regr[((size_t)b * 2 + 1) * HW + rem];
        float emb = 0.f;
        if (t == 0) emb = tl_tag[(size_t)b * HW + rem];
        else if (t == 1) emb = br_tag[(size_t)b * HW + rem];
        int o = bc * KTOP + tid;
        cs[o] = s2;
        cx[o] = (float)x + o0;
        cy[o] = (float)y + o1;
        ce[o] = emb;
        ccls[o] = cls;
    }
}

// ---- kernel 3: fused pairwise scoring + final top-1000 + centers ----
__global__ void __launch_bounds__(1024) k_pairfinal(
        const float* __restrict__ cs, const float* __restrict__ cx,
        const float* __restrict__ cy, const float* __restrict__ ce,
        const int* __restrict__ ccls, float* __restrict__ out) {
    int b = blockIdx.x;
    __shared__ float ts[KTOP], tx[KTOP], ty[KTOP], te[KTOP];
    __shared__ int   tc[KTOP];
    __shared__ float bs_[KTOP], bx[KTOP], by[KTOP], be[KTOP];
    __shared__ int   bcl[KTOP];
    __shared__ uint64_t acc[ACAP];
    __shared__ int aidx[ACAP];
    __shared__ int acnt_s;
    int tid = threadIdx.x;
    if (tid == 0) acnt_s = 0;
    if (tid < KTOP) {
        int o = (0 * NB + b) * KTOP + tid;
        ts[tid] = cs[o]; tx[tid] = cx[o]; ty[tid] = cy[o]; te[tid] = ce[o]; tc[tid] = ccls[o];
    } else if (tid >= 512 && tid < 512 + KTOP) {
        int k = tid - 512;
        int o = (1 * NB + b) * KTOP + k;
        bs_[k] = cs[o]; bx[k] = cx[o]; by[k] = cy[o]; be[k] = ce[o]; bcl[k] = ccls[o];
    }
    __syncthreads();
    for (int p = tid; p < NPAIR; p += 1024) {
        int i = p / KTOP, j = p - i * KTOP;
        bool rej = (tc[i] != bcl[j])
                 | (fabsf(te[i] - be[j]) > 0.5f)
                 | (bx[j] < tx[i])
                 | (by[j] < ty[i]);
        if (!rej) {
            float sc = (ts[i] + bs_[j]) * 0.5f;
            int pos = atomicAdd(&acnt_s, 1);
            if (pos < ACAP)
                acc[pos] = ((uint64_t)__float_as_uint(sc) << 32) | (uint32_t)(~(uint32_t)p);
        }
    }
    __syncthreads();
    int m = acnt_s; if (m > ACAP) m = ACAP;
    if (m <= 256) {
        for (int i = tid; i < 256; i += 1024) if (i >= m) acc[i] = 0;
        bitonic_desc<256>(acc);
    } else {
        for (int i = tid; i < ACAP; i += 1024) if (i >= m) acc[i] = 0;
        bitonic_desc<ACAP>(acc);
    }
    for (int i = tid; i < m; i += 1024) aidx[i] = (int)(~(uint32_t)acc[i]);
    __syncthreads();
    for (int d = tid; d < NDET; d += 1024) {
        int p; float sc;
        if (d < m) {
            p = aidx[d];
            sc = __uint_as_float((uint32_t)(acc[d] >> 32));
        } else {
            // (d-m)-th flat pair-index NOT in accepted set, ascending (stable -1 ties)
            int r = d - m;
            int idx = r;
            for (;;) {
                int c = 0;
                for (int a = 0; a < m; ++a) c += (aidx[a] <= idx) ? 1 : 0;
                int ni = r + c;
                if (ni == idx) break;
                idx = ni;
            }
            p = idx; sc = -1.f;
        }
        int i = p / KTOP, j = p - i * KTOP;
        int ot = (0 * NB + b) * KTOP + i;
        int ob = (1 * NB + b) * KTOP + j;
        float* dr = out + ((size_t)b * NDET + d) * 8;
        dr[0] = cx[ot]; dr[1] = cy[ot]; dr[2] = cx[ob]; dr[3] = cy[ob];
        dr[4] = sc; dr[5] = cs[ot]; dr[6] = cs[ob]; dr[7] = (float)ccls[ot];
    }
    if (tid < KTOP) {
        int oc = (2 * NB + b) * KTOP + tid;
        float* cr = out + (size_t)NB * NDET * 8 + ((size_t)b * KTOP + tid) * 4;
        cr[0] = cx[oc]; cr[1] = cy[oc]; cr[2] = (float)ccls[oc]; cr[3] = cs[oc];
    }
}

extern "C" void kernel_launch(void* const* d_in, const int* in_sizes, int n_in,
                              void* d_out, int out_size, void* d_ws, size_t ws_size,
                              hipStream_t stream) {
    const float* tl_heat = (const float*)d_in[0];
    const float* br_heat = (const float*)d_in[1];
    const float* ct_heat = (const float*)d_in[2];
    const float* tl_tag  = (const float*)d_in[3];
    const float* br_tag  = (const float*)d_in[4];
    const float* tl_regr = (const float*)d_in[5];
    const float* br_regr = (const float*)d_in[6];
    const float* ct_regr = (const float*)d_in[7];

    if (ws_size < (size_t)(OFF_SURV + 24 * 8 * 1024)) return;
    size_t rem = (ws_size - OFF_SURV) / (24 * 8);
    int scap = (int)((rem > SCAP_MAX) ? SCAP_MAX : rem);

    char* ws = (char*)d_ws;
    int*      scnt = (int*)(ws + OFF_SCNT);
    int*      ovf  = (int*)(ws + OFF_OVF);
    uint32_t* hist = (uint32_t*)(ws + OFF_HIST);
    float*    cs   = (float*)(ws + OFF_CS);
    float*    cx   = (float*)(ws + OFF_CX);
    float*    cy   = (float*)(ws + OFF_CY);
    float*    ce   = (float*)(ws + OFF_CE);
    int*      ccls = (int*)(ws + OFF_CCLS);
    uint64_t* surv = (uint64_t*)(ws + OFF_SURV);

    hipMemsetAsync(ws, 0, ZERO_BYTES, stream);

    k_nms<<<dim3(160, 24), 256, 0, stream>>>(tl_heat, br_heat, ct_heat,
                                             surv, scnt, ovf, hist, scap);
    k_collectsel<<<24, 1024, 0, stream>>>(hist, surv, scnt, ovf, scap,
                                          tl_heat, br_heat, ct_heat,
                                          tl_tag, br_tag,
                                          tl_regr, br_regr, ct_regr,
                                          cs, cx, cy, ce, ccls);
    k_pairfinal<<<NB, 1024, 0, stream>>>(cs, cx, cy, ce, ccls, (float*)d_out);
}

// Round 8
// 80.666 us; speedup vs baseline: 3.6980x; 1.4413x over previous
//
#include <hip/hip_runtime.h>
#include <cstdint>

// Problem constants (B=8, C=80, H=W=128, K=100, kernel=3, num_dets=1000)
#define NB    8
#define NC    80
#define HH    128
#define WW    128
#define HW    16384
#define CHW   1310720
#define KTOP  100
#define NDET  1000
#define NPAIR 10000
#define CAP   4096
#define ACAP  2048
#define NBINS 4096
#define BLK_SURV 1024     // LDS survivor staging cap per block (expect ~900)
#define SCAP_MAX 262144   // per-(tensor,batch) survivor cap; expected ~145K

// ---- workspace layout (bytes) ----
#define OFF_SCNT   0                         // int[24*32] (one counter per 128B)
#define OFF_CCNT   3072                      // int[24*32]
#define OFF_OVF    6144                      // int[32]
#define OFF_THR    6272                      // int[32]
#define OFF_HIST   6400                      // u32[24][4096]
#define ZERO_BYTES 399616                    // scnt+ccnt+ovf+thr+hist
#define OFF_CAND   399616                    // u64[24][4096]
#define OFF_CS     1186048                   // float[2400]
#define OFF_CX     1195648
#define OFF_CY     1205248
#define OFF_CE     1214848
#define OFF_CCLS   1224448                   // int[2400]
#define OFF_SURV   1234048                   // u64[24][scap]

// branchless, bit-identical to jax.nn.sigmoid's two-branch form
__device__ __forceinline__ float sigmoidf(float x) {
    float e = expf(-fabsf(x));
    return (x >= 0.f ? 1.f : e) / (1.f + e);
}

// ---- kernel 1: NMS + fused histogram + compacted survivor emission ----
__global__ void __launch_bounds__(256) k_nms(
        const float* __restrict__ tl, const float* __restrict__ br,
        const float* __restrict__ ct,
        uint64_t* __restrict__ surv, int* __restrict__ scnt,
        int* __restrict__ ovf, uint32_t* __restrict__ hist, int scap) {
    __shared__ uint32_t lh[NBINS];          // 16 KB
    __shared__ uint2    lsurv[BLK_SURV];    // 8 KB
    __shared__ int      woff[4];
    __shared__ int      gbase_s, tot_s;

    int tid = threadIdx.x;
    for (int i = tid; i < NBINS; i += 256) lh[i] = 0;

    int bc = blockIdx.y; int t = bc >> 3; int b = bc & 7;
    const float* heat = (t == 0) ? tl : (t == 1) ? br : ct;
    int chan = blockIdx.x >> 1;
    int half = blockIdx.x & 1;
    const float* cb = heat + (size_t)b * CHW + (size_t)chan * HW;
    int lane = tid & 63;
    int wid = tid >> 6;
    int band = (wid << 1) + (lane >> 5);             // 0..7
    int ybase = half * 64 + band * 8;                // 0..120
    int x0 = (lane & 31) << 2;
    const float NEG = -__builtin_inff();

    // phase A: 10 unconditional loads, pinned live
    float4 L[10];
    #pragma unroll
    for (int r = 0; r < 10; ++r) {
        int yy = ybase - 1 + r;
        int yc = min(max(yy, 0), HH - 1);
        L[r] = *(const float4*)(cb + yc * WW + x0);
    }
    #pragma unroll
    for (int r = 0; r < 10; ++r)
        asm volatile("" : "+v"(L[r].x), "+v"(L[r].y), "+v"(L[r].z), "+v"(L[r].w));
    if (ybase == 0)       L[0] = make_float4(NEG, NEG, NEG, NEG);
    if (ybase == HH - 8)  L[9] = make_float4(NEG, NEG, NEG, NEG);

    uint32_t mask = 0;
    #pragma unroll
    for (int j = 0; j < 8; ++j) {
        float c0 = fmaxf(fmaxf(L[j].x, L[j+1].x), L[j+2].x);
        float c1 = fmaxf(fmaxf(L[j].y, L[j+1].y), L[j+2].y);
        float c2 = fmaxf(fmaxf(L[j].z, L[j+1].z), L[j+2].z);
        float c3 = fmaxf(fmaxf(L[j].w, L[j+1].w), L[j+2].w);
        float cl = __shfl_up(c3, 1);
        float cr = __shfl_down(c0, 1);
        if (x0 == 0)      cl = NEG;
        if (x0 == WW - 4) cr = NEG;
        if (fmaxf(fmaxf(cl, c0), c1) == L[j+1].x) mask |= 1u << (j*4+0);
        if (fmaxf(fmaxf(c0, c1), c2) == L[j+1].y) mask |= 1u << (j*4+1);
        if (fmaxf(fmaxf(c1, c2), c3) == L[j+1].z) mask |= 1u << (j*4+2);
        if (fmaxf(fmaxf(c2, c3), cr) == L[j+1].w) mask |= 1u << (j*4+3);
    }

    // phase B: block-wide compaction into LDS
    int cnt = __popc(mask);
    int incl = cnt;
    #pragma unroll
    for (int d = 1; d < 64; d <<= 1) {
        int u = __shfl_up(incl, d);
        if (lane >= d) incl += u;
    }
    if (lane == 63) woff[wid] = incl;
    __syncthreads();
    if (tid == 0) {
        int s = 0;
        #pragma unroll
        for (int w = 0; w < 4; ++w) { int tw = woff[w]; woff[w] = s; s += tw; }
        tot_s = s;
        int gb = atomicAdd(&scnt[bc * 32], s);
        gbase_s = gb;
        if (s > BLK_SURV || gb + s > scap) ovf[bc] = 1;
    }
    __syncthreads();
    int base = woff[wid] + incl - cnt;
    if (mask) {
        int ib = chan * HW + ybase * WW + x0;
        #pragma unroll
        for (int j = 0; j < 8; ++j) {
            #pragma unroll
            for (int p = 0; p < 4; ++p) {
                if (mask & (1u << (j * 4 + p))) {
                    float v = (p == 0) ? L[j+1].x : (p == 1) ? L[j+1].y
                            : (p == 2) ? L[j+1].z : L[j+1].w;
                    if (base < BLK_SURV)
                        lsurv[base] = make_uint2(__float_as_uint(v),
                                                 (uint32_t)(ib + j * WW + p));
                    ++base;
                }
            }
        }
    }
    __syncthreads();

    // phase C: dense sigmoid + hist + coalesced store
    int total = tot_s; if (total > BLK_SURV) total = BLK_SURV;
    int gb = gbase_s;
    uint64_t* sv = surv + (size_t)bc * scap;
    for (int i = tid; i < total; i += 256) {
        uint2 e = lsurv[i];
        uint32_t bt = __float_as_uint(sigmoidf(__uint_as_float(e.x)));
        atomicAdd(&lh[bt >> 19], 1u);
        if (gb + i < scap)
            sv[gb + i] = ((uint64_t)bt << 32) | (uint32_t)(~e.y);
    }
    __syncthreads();
    uint32_t* gh = hist + (size_t)bc * NBINS;
    for (int i = tid; i < NBINS; i += 256) {
        uint32_t c = lh[i];
        if (c) atomicAdd(&gh[i], c);
    }
}

// on-the-fly key for the (never-expected) survivor-overflow fallback
__device__ uint64_t key_at(const float* __restrict__ hb, int i) {
    float v = hb[i];
    int rem = i & (HW - 1);
    int y = rem >> 7, x = rem & (WW - 1);
    bool mx = true;
    if (y > 0) {
        if (x > 0      && hb[i - WW - 1] > v) mx = false;
        if (              hb[i - WW    ] > v) mx = false;
        if (x < WW - 1 && hb[i - WW + 1] > v) mx = false;
    }
    if (x > 0      && hb[i - 1] > v) mx = false;
    if (x < WW - 1 && hb[i + 1] > v) mx = false;
    if (y < HH - 1) {
        if (x > 0      && hb[i + WW - 1] > v) mx = false;
        if (              hb[i + WW    ] > v) mx = false;
        if (x < WW - 1 && hb[i + WW + 1] > v) mx = false;
    }
    if (!mx) return 0;
    return ((uint64_t)__float_as_uint(sigmoidf(v)) << 32) | (uint32_t)(~(uint32_t)i);
}

// ---- kernel 2: parallel threshold find (24 blocks) ----
__global__ void __launch_bounds__(256) k_thresh(const uint32_t* __restrict__ hist,
                                                int* __restrict__ thr) {
    __shared__ uint32_t csum[256];
    int bc = blockIdx.x;
    const uint32_t* h = hist + (size_t)bc * NBINS;
    int tid = threadIdx.x;
    uint32_t bins[16];
    #pragma unroll
    for (int i = 0; i < 16; ++i) bins[i] = h[tid * 16 + i];
    if (tid == 0) bins[0] = 0;  // bin 0 excluded
    uint32_t s = 0;
    #pragma unroll
    for (int i = 0; i < 16; ++i) s += bins[i];
    csum[tid] = s;
    __syncthreads();
    for (int step = 1; step < 256; step <<= 1) {
        uint32_t add = (tid + step < 256) ? csum[tid + step] : 0;
        __syncthreads();
        csum[tid] += add;
        __syncthreads();
    }
    uint32_t inc = csum[tid];
    uint32_t above = (tid + 1 < 256) ? csum[tid + 1] : 0;
    if (tid == 0 && inc < KTOP) thr[bc] = 1;
    if (above < KTOP && inc >= KTOP) {
        uint32_t cum = above;
        int T = 1;
        #pragma unroll
        for (int i = 15; i >= 0; --i) {
            cum += bins[i];
            if (cum >= KTOP) { T = tid * 16 + i; break; }
        }
        thr[bc] = T;
    }
}

// ---- kernel 3: wide filter of survivors by bin >= T (fallback folded) ----
__global__ void __launch_bounds__(256) k_filter(
        const uint64_t* __restrict__ surv, const int* __restrict__ scnt,
        const int* __restrict__ ovf, int scap, const int* __restrict__ thr,
        const float* __restrict__ tl, const float* __restrict__ br,
        const float* __restrict__ ct,
        uint64_t* __restrict__ cand, int* __restrict__ ccnt) {
    int bc = blockIdx.y;
    int n = scnt[bc * 32];
    bool fb = (ovf[bc] != 0) || (n > scap);
    int T = thr[bc];
    if (!fb) {
        const uint64_t* sv = surv + (size_t)bc * scap;
        for (int i = blockIdx.x * 256 + threadIdx.x; i < n; i += 256 * 32) {
            uint64_t k = sv[i];
            if ((int)(uint32_t)(k >> 51) >= T) {
                int pos = atomicAdd(&ccnt[bc * 32], 1);
                if (pos < CAP) cand[(size_t)bc * CAP + pos] = k;
            }
        }
    } else {
        int t = bc >> 3; int b = bc & 7;
        const float* heat = (t == 0) ? tl : (t == 1) ? br : ct;
        const float* hb = heat + (size_t)b * CHW;
        for (int i = blockIdx.x * 256 + threadIdx.x; i < CHW; i += 256 * 32) {
            uint64_t k = key_at(hb, i);
            if (k && (int)(uint32_t)(k >> 51) >= T) {
                int pos = atomicAdd(&ccnt[bc * 32], 1);
                if (pos < CAP) cand[(size_t)bc * CAP + pos] = k;
            }
        }
    }
}

// descending bitonic sort of N u64 keys in LDS
template <int N>
__device__ void bitonic_desc(uint64_t* k) {
    for (int kk = 2; kk <= N; kk <<= 1) {
        for (int j = kk >> 1; j > 0; j >>= 1) {
            __syncthreads();
            for (int i = threadIdx.x; i < N; i += blockDim.x) {
                int l = i ^ j;
                if (l > i) {
                    uint64_t a = k[i], b = k[l];
                    bool up = ((i & kk) == 0);
                    if (up ? (a < b) : (a > b)) { k[i] = b; k[l] = a; }
                }
            }
        }
    }
    __syncthreads();
}

// ---- kernel 4: per (tensor,batch) sort candidates, emit top-100 ----
__global__ void __launch_bounds__(1024) k_select(
        const uint64_t* __restrict__ cand, const int* __restrict__ ccnt,
        const float* __restrict__ tl_tag, const float* __restrict__ br_tag,
        const float* __restrict__ tl_regr, const float* __restrict__ br_regr,
        const float* __restrict__ ct_regr,
        float* __restrict__ cs, float* __restrict__ cx, float* __restrict__ cy,
        float* __restrict__ ce, int* __restrict__ ccls) {
    __shared__ uint64_t keys[CAP];
    int bc = blockIdx.x; int t = bc >> 3; int b = bc & 7;
    int n = ccnt[bc * 32]; if (n > CAP) n = CAP;
    if (n <= 512) {
        for (int i = threadIdx.x; i < 512; i += 1024)
            keys[i] = (i < n) ? cand[(size_t)bc * CAP + i] : 0ull;
        bitonic_desc<512>(keys);
    } else {
        for (int i = threadIdx.x; i < CAP; i += 1024)
            keys[i] = (i < n) ? cand[(size_t)bc * CAP + i] : 0ull;
        bitonic_desc<CAP>(keys);
    }
    if (threadIdx.x < KTOP) {
        uint64_t key = keys[threadIdx.x];
        float s = __uint_as_float((uint32_t)(key >> 32));
        uint32_t idx = ~(uint32_t)key;
        int cls = (int)(idx >> 14);
        int rem = (int)(idx & (HW - 1));
        int y = rem >> 7, x = rem & (WW - 1);
        const float* regr = (t == 0) ? tl_regr : (t == 1) ? br_regr : ct_regr;
        float o0 = regr[((size_t)b * 2 + 0) * HW + rem];
        float o1 = regr[((size_t)b * 2 + 1) * HW + rem];
        float emb = 0.f;
        if (t == 0) emb = tl_tag[(size_t)b * HW + rem];
        else if (t == 1) emb = br_tag[(size_t)b * HW + rem];
        int o = bc * KTOP + threadIdx.x;
        cs[o] = s;
        cx[o] = (float)x + o0;
        cy[o] = (float)y + o1;
        ce[o] = emb;
        ccls[o] = cls;
    }
}

// ---- kernel 5: fused pairwise scoring + final top-1000 + centers ----
__global__ void __launch_bounds__(1024) k_pairfinal(
        const float* __restrict__ cs, const float* __restrict__ cx,
        const float* __restrict__ cy, const float* __restrict__ ce,
        const int* __restrict__ ccls, float* __restrict__ out) {
    int b = blockIdx.x;
    __shared__ float ts[KTOP], tx[KTOP], ty[KTOP], te[KTOP];
    __shared__ int   tc[KTOP];
    __shared__ float bs_[KTOP], bx[KTOP], by[KTOP], be[KTOP];
    __shared__ int   bcl[KTOP];
    __shared__ uint64_t acc[ACAP];
    __shared__ int aidx[ACAP];
    __shared__ int acnt_s;
    int tid = threadIdx.x;
    if (tid == 0) acnt_s = 0;
    if (tid < KTOP) {
        int o = (0 * NB + b) * KTOP + tid;
        ts[tid] = cs[o]; tx[tid] = cx[o]; ty[tid] = cy[o]; te[tid] = ce[o]; tc[tid] = ccls[o];
    } else if (tid >= 512 && tid < 512 + KTOP) {
        int k = tid - 512;
        int o = (1 * NB + b) * KTOP + k;
        bs_[k] = cs[o]; bx[k] = cx[o]; by[k] = cy[o]; be[k] = ce[o]; bcl[k] = ccls[o];
    }
    __syncthreads();
    for (int p = tid; p < NPAIR; p += 1024) {
        int i = p / KTOP, j = p - i * KTOP;
        bool rej = (tc[i] != bcl[j])
                 | (fabsf(te[i] - be[j]) > 0.5f)
                 | (bx[j] < tx[i])
                 | (by[j] < ty[i]);
        if (!rej) {
            float sc = (ts[i] + bs_[j]) * 0.5f;
            int pos = atomicAdd(&acnt_s, 1);
            if (pos < ACAP)
                acc[pos] = ((uint64_t)__float_as_uint(sc) << 32) | (uint32_t)(~(uint32_t)p);
        }
    }
    __syncthreads();
    int m = acnt_s; if (m > ACAP) m = ACAP;
    if (m <= 256) {
        for (int i = tid; i < 256; i += 1024) if (i >= m) acc[i] = 0;
        bitonic_desc<256>(acc);
    } else {
        for (int i = tid; i < ACAP; i += 1024) if (i >= m) acc[i] = 0;
        bitonic_desc<ACAP>(acc);
    }
    for (int i = tid; i < m; i += 1024) aidx[i] = (int)(~(uint32_t)acc[i]);
    __syncthreads();
    for (int d = tid; d < NDET; d += 1024) {
        int p; float sc;
        if (d < m) {
            p = aidx[d];
            sc = __uint_as_float((uint32_t)(acc[d] >> 32));
        } else {
            // (d-m)-th flat pair-index NOT in accepted set, ascending (stable -1 ties)
            int r = d - m;
            int idx = r;
            for (;;) {
                int c = 0;
                for (int a = 0; a < m; ++a) c += (aidx[a] <= idx) ? 1 : 0;
                int ni = r + c;
                if (ni == idx) break;
                idx = ni;
            }
            p = idx; sc = -1.f;
        }
        int i = p / KTOP, j = p - i * KTOP;
        int ot = (0 * NB + b) * KTOP + i;
        int ob = (1 * NB + b) * KTOP + j;
        float* dr = out + ((size_t)b * NDET + d) * 8;
        dr[0] = cx[ot]; dr[1] = cy[ot]; dr[2] = cx[ob]; dr[3] = cy[ob];
        dr[4] = sc; dr[5] = cs[ot]; dr[6] = cs[ob]; dr[7] = (float)ccls[ot];
    }
    if (tid < KTOP) {
        int oc = (2 * NB + b) * KTOP + tid;
        float* cr = out + (size_t)NB * NDET * 8 + ((size_t)b * KTOP + tid) * 4;
        cr[0] = cx[oc]; cr[1] = cy[oc]; cr[2] = (float)ccls[oc]; cr[3] = cs[oc];
    }
}

extern "C" void kernel_launch(void* const* d_in, const int* in_sizes, int n_in,
                              void* d_out, int out_size, void* d_ws, size_t ws_size,
                              hipStream_t stream) {
    const float* tl_heat = (const float*)d_in[0];
    const float* br_heat = (const float*)d_in[1];
    const float* ct_heat = (const float*)d_in[2];
    const float* tl_tag  = (const float*)d_in[3];
    const float* br_tag  = (const float*)d_in[4];
    const float* tl_regr = (const float*)d_in[5];
    const float* br_regr = (const float*)d_in[6];
    const float* ct_regr = (const float*)d_in[7];

    if (ws_size < (size_t)(OFF_SURV + 24 * 8 * 1024)) return;
    size_t rem = (ws_size - OFF_SURV) / (24 * 8);
    int scap = (int)((rem > SCAP_MAX) ? SCAP_MAX : rem);

    char* ws = (char*)d_ws;
    int*      scnt = (int*)(ws + OFF_SCNT);
    int*      ccnt = (int*)(ws + OFF_CCNT);
    int*      ovf  = (int*)(ws + OFF_OVF);
    int*      thr  = (int*)(ws + OFF_THR);
    uint32_t* hist = (uint32_t*)(ws + OFF_HIST);
    uint64_t* cand = (uint64_t*)(ws + OFF_CAND);
    float*    cs   = (float*)(ws + OFF_CS);
    float*    cx   = (float*)(ws + OFF_CX);
    float*    cy   = (float*)(ws + OFF_CY);
    float*    ce   = (float*)(ws + OFF_CE);
    int*      ccls = (int*)(ws + OFF_CCLS);
    uint64_t* surv = (uint64_t*)(ws + OFF_SURV);

    hipMemsetAsync(ws, 0, ZERO_BYTES, stream);

    k_nms<<<dim3(160, 24), 256, 0, stream>>>(tl_heat, br_heat, ct_heat,
                                             surv, scnt, ovf, hist, scap);
    k_thresh<<<24, 256, 0, stream>>>(hist, thr);
    k_filter<<<dim3(32, 24), 256, 0, stream>>>(surv, scnt, ovf, scap, thr,
                                               tl_heat, br_heat, ct_heat,
                                               cand, ccnt);
    k_select<<<24, 1024, 0, stream>>>(cand, ccnt, tl_tag, br_tag,
                                      tl_regr, br_regr, ct_regr,
                                      cs, cx, cy, ce, ccls);
    k_pairfinal<<<NB, 1024, 0, stream>>>(cs, cx, cy, ce, ccls, (float*)d_out);
}

// Round 9
// 78.587 us; speedup vs baseline: 3.7958x; 1.0264x over previous
//
#include <hip/hip_runtime.h>
#include <cstdint>

// Problem constants (B=8, C=80, H=W=128, K=100, kernel=3, num_dets=1000)
#define NB    8
#define NC    80
#define HH    128
#define WW    128
#define HW    16384
#define CHW   1310720
#define KTOP  100
#define NDET  1000
#define NPAIR 10000
#define CAP   4096
#define ACAP  2048
#define NBINS 4096
#define BLK_SURV 1024     // per-block survivor segment (expect ~900)
#define NSEG  160         // k_nms blocks per (tensor,batch)

// ---- workspace layout (bytes) ----
#define OFF_CCNT   0                         // int[24*32] (one counter per 128B)
#define OFF_OVF    3072                      // int[32]
#define OFF_HIST   3200                      // u32[24][4096]
#define ZERO_BYTES 396416                    // ccnt+ovf+hist
#define OFF_THR    396416                    // int[32]
#define OFF_BLKCNT 396544                    // int[24*160]
#define OFF_CAND   411904                    // u64[24][4096]
#define OFF_CS     1198336                   // float[2400]
#define OFF_CX     1207936
#define OFF_CY     1217536
#define OFF_CE     1227136
#define OFF_CCLS   1236736                   // int[2400]
#define OFF_SURV   1246336                   // u64[24][160][1024] = 31.5 MB
#define WS_NEEDED  (OFF_SURV + 24*NSEG*BLK_SURV*8)

// branchless, bit-identical to jax.nn.sigmoid's two-branch form
__device__ __forceinline__ float sigmoidf(float x) {
    float e = expf(-fabsf(x));
    return (x >= 0.f ? 1.f : e) / (1.f + e);
}

// ---- kernel 1: NMS + compacted survivor segments + fused histogram ----
// No global atomics on the critical path: each block owns segment
// surv[bc][blockIdx.x][0..1023] and writes its count with a plain store.
__global__ void __launch_bounds__(256, 6) k_nms(
        const float* __restrict__ tl, const float* __restrict__ br,
        const float* __restrict__ ct,
        uint64_t* __restrict__ surv, int* __restrict__ blkcnt,
        int* __restrict__ ovf, uint32_t* __restrict__ hist) {
    __shared__ uint32_t lh2[NBINS / 2];     // u16-packed bins, 8 KB
    __shared__ uint2    lsurv[BLK_SURV];    // 8 KB
    __shared__ int      woff[4];

    int tid = threadIdx.x;
    for (int i = tid; i < NBINS / 2; i += 256) lh2[i] = 0;

    int bc = blockIdx.y; int t = bc >> 3; int b = bc & 7;
    const float* heat = (t == 0) ? tl : (t == 1) ? br : ct;
    int seg = blockIdx.x;
    int chan = seg >> 1;
    int half = seg & 1;
    const float* cb = heat + (size_t)b * CHW + (size_t)chan * HW;
    int lane = tid & 63;
    int wid = tid >> 6;
    int band = (wid << 1) + (lane >> 5);             // 0..7
    int ybase = half * 64 + band * 8;                // 0..120
    int x0 = (lane & 31) << 2;
    const float NEG = -__builtin_inff();

    // phase A: 10 unconditional loads (clamped row), pinned live
    float4 L[10];
    #pragma unroll
    for (int r = 0; r < 10; ++r) {
        int yy = ybase - 1 + r;
        int yc = min(max(yy, 0), HH - 1);
        L[r] = *(const float4*)(cb + yc * WW + x0);
    }
    #pragma unroll
    for (int r = 0; r < 10; ++r)
        asm volatile("" : "+v"(L[r].x), "+v"(L[r].y), "+v"(L[r].z), "+v"(L[r].w));
    if (ybase == 0)       L[0] = make_float4(NEG, NEG, NEG, NEG);
    if (ybase == HH - 8)  L[9] = make_float4(NEG, NEG, NEG, NEG);

    uint32_t mask = 0;
    #pragma unroll
    for (int j = 0; j < 8; ++j) {
        float c0 = fmaxf(fmaxf(L[j].x, L[j+1].x), L[j+2].x);
        float c1 = fmaxf(fmaxf(L[j].y, L[j+1].y), L[j+2].y);
        float c2 = fmaxf(fmaxf(L[j].z, L[j+1].z), L[j+2].z);
        float c3 = fmaxf(fmaxf(L[j].w, L[j+1].w), L[j+2].w);
        float cl = __shfl_up(c3, 1);
        float cr = __shfl_down(c0, 1);
        if (x0 == 0)      cl = NEG;
        if (x0 == WW - 4) cr = NEG;
        if (fmaxf(fmaxf(cl, c0), c1) == L[j+1].x) mask |= 1u << (j*4+0);
        if (fmaxf(fmaxf(c0, c1), c2) == L[j+1].y) mask |= 1u << (j*4+1);
        if (fmaxf(fmaxf(c1, c2), c3) == L[j+1].z) mask |= 1u << (j*4+2);
        if (fmaxf(fmaxf(c2, c3), cr) == L[j+1].w) mask |= 1u << (j*4+3);
    }

    // phase B: block-wide compaction into LDS (no global traffic)
    int cnt = __popc(mask);
    int incl = cnt;
    #pragma unroll
    for (int d = 1; d < 64; d <<= 1) {
        int u = __shfl_up(incl, d);
        if (lane >= d) incl += u;
    }
    if (lane == 63) woff[wid] = incl;
    __syncthreads();
    int pre = 0, total = 0;
    #pragma unroll
    for (int w = 0; w < 4; ++w) {
        int tw = woff[w];
        if (w < wid) pre += tw;
        total += tw;
    }
    int base = pre + incl - cnt;
    if (mask) {
        int ib = chan * HW + ybase * WW + x0;
        #pragma unroll
        for (int j = 0; j < 8; ++j) {
            #pragma unroll
            for (int p = 0; p < 4; ++p) {
                if (mask & (1u << (j * 4 + p))) {
                    float v = (p == 0) ? L[j+1].x : (p == 1) ? L[j+1].y
                            : (p == 2) ? L[j+1].z : L[j+1].w;
                    if (base < BLK_SURV)
                        lsurv[base] = make_uint2(__float_as_uint(v),
                                                 (uint32_t)(ib + j * WW + p));
                    ++base;
                }
            }
        }
    }
    __syncthreads();

    // phase C: dense sigmoid + u16 hist + coalesced segment store
    if (tid == 0) {
        blkcnt[bc * NSEG + seg] = min(total, BLK_SURV);
        if (total > BLK_SURV) ovf[bc] = 1;
    }
    int tt = min(total, BLK_SURV);
    uint64_t* sv = surv + ((size_t)bc * NSEG + seg) * BLK_SURV;
    for (int i = tid; i < tt; i += 256) {
        uint2 e = lsurv[i];
        uint32_t bt = __float_as_uint(sigmoidf(__uint_as_float(e.x)));
        uint32_t bin = bt >> 19;
        atomicAdd(&lh2[bin >> 1], 1u << ((bin & 1) * 16));
        sv[i] = ((uint64_t)bt << 32) | (uint32_t)(~e.y);
    }
    __syncthreads();
    uint32_t* gh = hist + (size_t)bc * NBINS;
    for (int i = tid; i < NBINS / 2; i += 256) {
        uint32_t v = lh2[i];
        uint32_t lo = v & 0xFFFFu, hi = v >> 16;
        if (lo) atomicAdd(&gh[2 * i], lo);
        if (hi) atomicAdd(&gh[2 * i + 1], hi);
    }
}

// on-the-fly key for the (never-expected) survivor-overflow fallback
__device__ uint64_t key_at(const float* __restrict__ hb, int i) {
    float v = hb[i];
    int rem = i & (HW - 1);
    int y = rem >> 7, x = rem & (WW - 1);
    bool mx = true;
    if (y > 0) {
        if (x > 0      && hb[i - WW - 1] > v) mx = false;
        if (              hb[i - WW    ] > v) mx = false;
        if (x < WW - 1 && hb[i - WW + 1] > v) mx = false;
    }
    if (x > 0      && hb[i - 1] > v) mx = false;
    if (x < WW - 1 && hb[i + 1] > v) mx = false;
    if (y < HH - 1) {
        if (x > 0      && hb[i + WW - 1] > v) mx = false;
        if (              hb[i + WW    ] > v) mx = false;
        if (x < WW - 1 && hb[i + WW + 1] > v) mx = false;
    }
    if (!mx) return 0;
    return ((uint64_t)__float_as_uint(sigmoidf(v)) << 32) | (uint32_t)(~(uint32_t)i);
}

// ---- kernel 2: parallel threshold find (24 blocks) ----
__global__ void __launch_bounds__(256) k_thresh(const uint32_t* __restrict__ hist,
                                                int* __restrict__ thr) {
    __shared__ uint32_t csum[256];
    int bc = blockIdx.x;
    const uint32_t* h = hist + (size_t)bc * NBINS;
    int tid = threadIdx.x;
    uint32_t bins[16];
    #pragma unroll
    for (int i = 0; i < 16; ++i) bins[i] = h[tid * 16 + i];
    if (tid == 0) bins[0] = 0;  // bin 0 excluded
    uint32_t s = 0;
    #pragma unroll
    for (int i = 0; i < 16; ++i) s += bins[i];
    csum[tid] = s;
    __syncthreads();
    for (int step = 1; step < 256; step <<= 1) {
        uint32_t add = (tid + step < 256) ? csum[tid + step] : 0;
        __syncthreads();
        csum[tid] += add;
        __syncthreads();
    }
    uint32_t inc = csum[tid];
    uint32_t above = (tid + 1 < 256) ? csum[tid + 1] : 0;
    if (tid == 0 && inc < KTOP) thr[bc] = 1;
    if (above < KTOP && inc >= KTOP) {
        uint32_t cum = above;
        int T = 1;
        #pragma unroll
        for (int i = 15; i >= 0; --i) {
            cum += bins[i];
            if (cum >= KTOP) { T = tid * 16 + i; break; }
        }
        thr[bc] = T;
    }
}

// ---- kernel 3: wide filter of segmented survivors by bin >= T ----
__global__ void __launch_bounds__(256) k_filter(
        const uint64_t* __restrict__ surv, const int* __restrict__ blkcnt,
        const int* __restrict__ ovf, const int* __restrict__ thr,
        const float* __restrict__ tl, const float* __restrict__ br,
        const float* __restrict__ ct,
        uint64_t* __restrict__ cand, int* __restrict__ ccnt) {
    int bc = blockIdx.y;
    int T = thr[bc];
    if (!ovf[bc]) {
        const uint64_t* sv = surv + (size_t)bc * NSEG * BLK_SURV;
        const int* bcnt = blkcnt + bc * NSEG;
        for (int i = blockIdx.x * 256 + threadIdx.x; i < NSEG * BLK_SURV;
             i += 64 * 256) {
            int seg = i >> 10, pos = i & (BLK_SURV - 1);
            if (pos < bcnt[seg]) {
                uint64_t k = sv[i];
                if ((int)(uint32_t)(k >> 51) >= T) {
                    int pc = atomicAdd(&ccnt[bc * 32], 1);
                    if (pc < CAP) cand[(size_t)bc * CAP + pc] = k;
                }
            }
        }
    } else {
        int t = bc >> 3; int b = bc & 7;
        const float* heat = (t == 0) ? tl : (t == 1) ? br : ct;
        const float* hb = heat + (size_t)b * CHW;
        for (int i = blockIdx.x * 256 + threadIdx.x; i < CHW; i += 64 * 256) {
            uint64_t k = key_at(hb, i);
            if (k && (int)(uint32_t)(k >> 51) >= T) {
                int pc = atomicAdd(&ccnt[bc * 32], 1);
                if (pc < CAP) cand[(size_t)bc * CAP + pc] = k;
            }
        }
    }
}

// descending bitonic sort of N u64 keys in LDS
template <int N>
__device__ void bitonic_desc(uint64_t* k) {
    for (int kk = 2; kk <= N; kk <<= 1) {
        for (int j = kk >> 1; j > 0; j >>= 1) {
            __syncthreads();
            for (int i = threadIdx.x; i < N; i += blockDim.x) {
                int l = i ^ j;
                if (l > i) {
                    uint64_t a = k[i], b = k[l];
                    bool up = ((i & kk) == 0);
                    if (up ? (a < b) : (a > b)) { k[i] = b; k[l] = a; }
                }
            }
        }
    }
    __syncthreads();
}

// ---- kernel 4: per (tensor,batch) sort candidates, emit top-100 ----
__global__ void __launch_bounds__(1024) k_select(
        const uint64_t* __restrict__ cand, const int* __restrict__ ccnt,
        const float* __restrict__ tl_tag, const float* __restrict__ br_tag,
        const float* __restrict__ tl_regr, const float* __restrict__ br_regr,
        const float* __restrict__ ct_regr,
        float* __restrict__ cs, float* __restrict__ cx, float* __restrict__ cy,
        float* __restrict__ ce, int* __restrict__ ccls) {
    __shared__ uint64_t keys[CAP];
    int bc = blockIdx.x; int t = bc >> 3; int b = bc & 7;
    int n = ccnt[bc * 32]; if (n > CAP) n = CAP;
    if (n <= 512) {
        for (int i = threadIdx.x; i < 512; i += 1024)
            keys[i] = (i < n) ? cand[(size_t)bc * CAP + i] : 0ull;
        bitonic_desc<512>(keys);
    } else {
        for (int i = threadIdx.x; i < CAP; i += 1024)
            keys[i] = (i < n) ? cand[(size_t)bc * CAP + i] : 0ull;
        bitonic_desc<CAP>(keys);
    }
    if (threadIdx.x < KTOP) {
        uint64_t key = keys[threadIdx.x];
        float s = __uint_as_float((uint32_t)(key >> 32));
        uint32_t idx = ~(uint32_t)key;
        int cls = (int)(idx >> 14);
        int rem = (int)(idx & (HW - 1));
        int y = rem >> 7, x = rem & (WW - 1);
        const float* regr = (t == 0) ? tl_regr : (t == 1) ? br_regr : ct_regr;
        float o0 = regr[((size_t)b * 2 + 0) * HW + rem];
        float o1 = regr[((size_t)b * 2 + 1) * HW + rem];
        float emb = 0.f;
        if (t == 0) emb = tl_tag[(size_t)b * HW + rem];
        else if (t == 1) emb = br_tag[(size_t)b * HW + rem];
        int o = bc * KTOP + threadIdx.x;
        cs[o] = s;
        cx[o] = (float)x + o0;
        cy[o] = (float)y + o1;
        ce[o] = emb;
        ccls[o] = cls;
    }
}

// ---- kernel 5: fused pairwise scoring + final top-1000 + centers ----
__global__ void __launch_bounds__(1024) k_pairfinal(
        const float* __restrict__ cs, const float* __restrict__ cx,
        const float* __restrict__ cy, const float* __restrict__ ce,
        const int* __restrict__ ccls, float* __restrict__ out) {
    int b = blockIdx.x;
    __shared__ float ts[KTOP], tx[KTOP], ty[KTOP], te[KTOP];
    __shared__ int   tc[KTOP];
    __shared__ float bs_[KTOP], bx[KTOP], by[KTOP], be[KTOP];
    __shared__ int   bcl[KTOP];
    __shared__ uint64_t acc[ACAP];
    __shared__ int aidx[ACAP];
    __shared__ int acnt_s;
    int tid = threadIdx.x;
    if (tid == 0) acnt_s = 0;
    if (tid < KTOP) {
        int o = (0 * NB + b) * KTOP + tid;
        ts[tid] = cs[o]; tx[tid] = cx[o]; ty[tid] = cy[o]; te[tid] = ce[o]; tc[tid] = ccls[o];
    } else if (tid >= 512 && tid < 512 + KTOP) {
        int k = tid - 512;
        int o = (1 * NB + b) * KTOP + k;
        bs_[k] = cs[o]; bx[k] = cx[o]; by[k] = cy[o]; be[k] = ce[o]; bcl[k] = ccls[o];
    }
    __syncthreads();
    for (int p = tid; p < NPAIR; p += 1024) {
        int i = p / KTOP, j = p - i * KTOP;
        bool rej = (tc[i] != bcl[j])
                 | (fabsf(te[i] - be[j]) > 0.5f)
                 | (bx[j] < tx[i])
                 | (by[j] < ty[i]);
        if (!rej) {
            float sc = (ts[i] + bs_[j]) * 0.5f;
            int pos = atomicAdd(&acnt_s, 1);
            if (pos < ACAP)
                acc[pos] = ((uint64_t)__float_as_uint(sc) << 32) | (uint32_t)(~(uint32_t)p);
        }
    }
    __syncthreads();
    int m = acnt_s; if (m > ACAP) m = ACAP;
    if (m <= 256) {
        for (int i = tid; i < 256; i += 1024) if (i >= m) acc[i] = 0;
        bitonic_desc<256>(acc);
    } else {
        for (int i = tid; i < ACAP; i += 1024) if (i >= m) acc[i] = 0;
        bitonic_desc<ACAP>(acc);
    }
    for (int i = tid; i < m; i += 1024) aidx[i] = (int)(~(uint32_t)acc[i]);
    __syncthreads();
    for (int d = tid; d < NDET; d += 1024) {
        int p; float sc;
        if (d < m) {
            p = aidx[d];
            sc = __uint_as_float((uint32_t)(acc[d] >> 32));
        } else {
            // (d-m)-th flat pair-index NOT in accepted set, ascending (stable -1 ties)
            int r = d - m;
            int idx = r;
            for (;;) {
                int c = 0;
                for (int a = 0; a < m; ++a) c += (aidx[a] <= idx) ? 1 : 0;
                int ni = r + c;
                if (ni == idx) break;
                idx = ni;
            }
            p = idx; sc = -1.f;
        }
        int i = p / KTOP, j = p - i * KTOP;
        int ot = (0 * NB + b) * KTOP + i;
        int ob = (1 * NB + b) * KTOP + j;
        float* dr = out + ((size_t)b * NDET + d) * 8;
        dr[0] = cx[ot]; dr[1] = cy[ot]; dr[2] = cx[ob]; dr[3] = cy[ob];
        dr[4] = sc; dr[5] = cs[ot]; dr[6] = cs[ob]; dr[7] = (float)ccls[ot];
    }
    if (tid < KTOP) {
        int oc = (2 * NB + b) * KTOP + tid;
        float* cr = out + (size_t)NB * NDET * 8 + ((size_t)b * KTOP + tid) * 4;
        cr[0] = cx[oc]; cr[1] = cy[oc]; cr[2] = (float)ccls[oc]; cr[3] = cs[oc];
    }
}

extern "C" void kernel_launch(void* const* d_in, const int* in_sizes, int n_in,
                              void* d_out, int out_size, void* d_ws, size_t ws_size,
                              hipStream_t stream) {
    const float* tl_heat = (const float*)d_in[0];
    const float* br_heat = (const float*)d_in[1];
    const float* ct_heat = (const float*)d_in[2];
    const float* tl_tag  = (const float*)d_in[3];
    const float* br_tag  = (const float*)d_in[4];
    const float* tl_regr = (const float*)d_in[5];
    const float* br_regr = (const float*)d_in[6];
    const float* ct_regr = (const float*)d_in[7];

    if (ws_size < (size_t)WS_NEEDED) return;   // ~32.7 MB

    char* ws = (char*)d_ws;
    int*      ccnt   = (int*)(ws + OFF_CCNT);
    int*      ovf    = (int*)(ws + OFF_OVF);
    uint32_t* hist   = (uint32_t*)(ws + OFF_HIST);
    int*      thr    = (int*)(ws + OFF_THR);
    int*      blkcnt = (int*)(ws + OFF_BLKCNT);
    uint64_t* cand   = (uint64_t*)(ws + OFF_CAND);
    float*    cs     = (float*)(ws + OFF_CS);
    float*    cx     = (float*)(ws + OFF_CX);
    float*    cy     = (float*)(ws + OFF_CY);
    float*    ce     = (float*)(ws + OFF_CE);
    int*      ccls   = (int*)(ws + OFF_CCLS);
    uint64_t* surv   = (uint64_t*)(ws + OFF_SURV);

    hipMemsetAsync(ws, 0, ZERO_BYTES, stream);   // ccnt + ovf + hist

    k_nms<<<dim3(NSEG, 24), 256, 0, stream>>>(tl_heat, br_heat, ct_heat,
                                              surv, blkcnt, ovf, hist);
    k_thresh<<<24, 256, 0, stream>>>(hist, thr);
    k_filter<<<dim3(64, 24), 256, 0, stream>>>(surv, blkcnt, ovf, thr,
                                               tl_heat, br_heat, ct_heat,
                                               cand, ccnt);
    k_select<<<24, 1024, 0, stream>>>(cand, ccnt, tl_tag, br_tag,
                                      tl_regr, br_regr, ct_regr,
                                      cs, cx, cy, ce, ccls);
    k_pairfinal<<<NB, 1024, 0, stream>>>(cs, cx, cy, ce, ccls, (float*)d_out);
}